// Round 10
// baseline (267.615 us; speedup 1.0000x reference)
//
#include <hip/hip_runtime.h>
#include <hip/hip_bf16.h>

#define CAP 32   // padded adjacency slots per node per sign (Poisson λ≈6.25)

typedef __attribute__((ext_vector_type(8))) short bf16x8;
typedef __attribute__((ext_vector_type(4))) float f32x4;

#define MFMA(a, b, c) __builtin_amdgcn_mfma_f32_16x16x32_bf16(a, b, c, 0, 0, 0)

__device__ __forceinline__ unsigned short bf16rn(float f) {
    unsigned u = __builtin_bit_cast(unsigned, f);
    u += 0x7fffu + ((u >> 16) & 1u);
    return (unsigned short)(u >> 16);
}
__device__ __forceinline__ float bf16lo(unsigned u) {
    return __builtin_bit_cast(float, u << 16);
}
__device__ __forceinline__ float bf16hi(unsigned u) {
    return __builtin_bit_cast(float, u & 0xffff0000u);
}
__device__ __forceinline__ unsigned pack2(float a, float b) {
    return (unsigned)bf16rn(a) | ((unsigned)bf16rn(b) << 16);
}
__device__ __forceinline__ bf16x8 packbf8(const float* p) {
    bf16x8 r;
    #pragma unroll
    for (int j = 0; j < 8; ++j) r[j] = (short)bf16rn(p[j]);
    return r;
}

// B-frag from row-major f32 W[K][NN]: elem j = W[kt*32 + q*8 + j][ct*16 + c]
__device__ __forceinline__ bf16x8 wfrag(const float* __restrict__ W, int NN,
                                        int kt, int ct, int q, int c) {
    const float* base = W + (kt * 32 + q * 8) * NN + ct * 16 + c;
    float t[8];
    #pragma unroll
    for (int j = 0; j < 8; ++j) t[j] = base[j * NN];
    return packbf8(t);
}

// A-frag: row-major bf16 source, contiguous 32-col window starting at cw
__device__ __forceinline__ bf16x8 afrag_bf16(const __hip_bfloat16* row, int cw, int q) {
    return *(const bf16x8*)((const short*)row + cw + q * 8);
}

// A-frag from a wave-private LDS row (stride-132 short), window cw, q8=lane>>4
__device__ __forceinline__ bf16x8 lfrag(const short* lrow, int cw, int q8) {
    const uint2* p = (const uint2*)(lrow + cw + q8 * 8);
    uint2 lo = p[0], hi = p[1];
    uint4 u;
    u.x = lo.x; u.y = lo.y; u.z = hi.x; u.w = hi.y;
    return __builtin_bit_cast(bf16x8, u);
}

// ---------------------------------------------------------------------------
// Fused: adjacency build (4 edges/thread) + x->bf16 cast.
// ---------------------------------------------------------------------------
__global__ __launch_bounds__(256) void pg_build_cast(
    const int* __restrict__ ei,
    int* __restrict__ plist, int* __restrict__ nlist,
    int* __restrict__ pcur, int* __restrict__ ncur, int E, int buildBlocks,
    const float* __restrict__ x, __hip_bfloat16* __restrict__ xb, int nx)
{
    int b = blockIdx.x;
    if (b >= buildBlocks) {
        int i = ((b - buildBlocks) * 256 + threadIdx.x) * 4;
        if (i < nx) {
            float4 v = *(const float4*)(x + i);
            ushort4 o;
            o.x = bf16rn(v.x); o.y = bf16rn(v.y);
            o.z = bf16rn(v.z); o.w = bf16rn(v.w);
            *(ushort4*)((unsigned short*)xb + i) = o;
        }
        return;
    }
    int e0 = (b * 256 + threadIdx.x) * 4;
    int s[4], d[4], sg[4];
    bool ok[4];
    #pragma unroll
    for (int k = 0; k < 4; ++k) {
        int e = e0 + k;
        ok[k] = (e < E);
        int ee = ok[k] ? e : 0;
        s[k]  = ei[3 * ee + 0];
        d[k]  = ei[3 * ee + 1];
        sg[k] = ei[3 * ee + 2];
    }
    int slot[4];
    int* dstl[4];
    #pragma unroll
    for (int k = 0; k < 4; ++k) {
        int* cur = (sg[k] > 0) ? pcur : ncur;
        dstl[k]  = ((sg[k] > 0) ? plist : nlist) + (size_t)d[k] * CAP;
        slot[k]  = ok[k] ? atomicAdd(cur + d[k], 1) : CAP;
    }
    #pragma unroll
    for (int k = 0; k < 4; ++k)
        if (slot[k] < CAP) dstl[k][slot[k]] = s[k];
}

// ===========================================================================
// Fused layer kernels: per wave, 16 nodes.
//   gather phase: masked slot-loads (no dummy transactions), 4-slot ILP;
//     means -> wave-private LDS tile [16][132] (pos cols 0..63, neg 64..127)
//   gemm phase: MFMA on LDS A-frags + global bf16 rows.
// ===========================================================================

#define GATHER_16NODES(SRC)                                                     \
    for (int g = 0; g < 4; ++g) {                                               \
        int i0 = base + g * 4;                                                  \
        int pd[4], nd[4], pde[4], nde[4], pl[4], nl[4];                         \
        _Pragma("unroll")                                                       \
        for (int n = 0; n < 4; ++n) {                                           \
            int i = min(i0 + n, N - 1);                                         \
            pd[n] = __builtin_amdgcn_readfirstlane(pcur[i]);                    \
            nd[n] = __builtin_amdgcn_readfirstlane(ncur[i]);                    \
            pde[n] = min(pd[n], CAP);                                           \
            nde[n] = min(nd[n], CAP);                                           \
            pl[n] = plist[(size_t)i * CAP + (lane & 31)];                       \
            nl[n] = nlist[(size_t)i * CAP + (lane & 31)];                       \
        }                                                                       \
        int maxd = 0;                                                           \
        _Pragma("unroll")                                                       \
        for (int n = 0; n < 4; ++n) maxd = max(maxd, max(pde[n], nde[n]));      \
        float ps[4][4], ns[4][4];                                               \
        _Pragma("unroll")                                                       \
        for (int n = 0; n < 4; ++n)                                             \
            _Pragma("unroll")                                                   \
            for (int r = 0; r < 4; ++r) { ps[n][r] = 0.f; ns[n][r] = 0.f; }     \
        _Pragma("unroll 1")                                                     \
        for (int e = 0; e < maxd; e += 4) {                                     \
            _Pragma("unroll")                                                   \
            for (int n = 0; n < 4; ++n) {                                       \
                int p0 = __builtin_amdgcn_readlane(pl[n], (e+0) < pde[n] ? e+0 : 0); \
                int p1 = __builtin_amdgcn_readlane(pl[n], (e+1) < pde[n] ? e+1 : 0); \
                int p2 = __builtin_amdgcn_readlane(pl[n], (e+2) < pde[n] ? e+2 : 0); \
                int p3 = __builtin_amdgcn_readlane(pl[n], (e+3) < pde[n] ? e+3 : 0); \
                int m0 = __builtin_amdgcn_readlane(nl[n], (e+0) < nde[n] ? e+0 : 0); \
                int m1 = __builtin_amdgcn_readlane(nl[n], (e+1) < nde[n] ? e+1 : 0); \
                int m2 = __builtin_amdgcn_readlane(nl[n], (e+2) < nde[n] ? e+2 : 0); \
                int m3 = __builtin_amdgcn_readlane(nl[n], (e+3) < nde[n] ? e+3 : 0); \
                unsigned sp = (unsigned)(grp == 0 ? p0 : grp == 1 ? p1 : grp == 2 ? p2 : p3); \
                unsigned sn = (unsigned)(grp == 0 ? m0 : grp == 1 ? m1 : grp == 2 ? m2 : m3); \
                if (e + grp < pde[n]) {                                         \
                    sp = sp < (unsigned)N ? sp : 0u;                            \
                    uint2 pv = *((const uint2*)((SRC) + ((size_t)sp << 6)) + q);\
                    ps[n][0] += bf16lo(pv.x); ps[n][1] += bf16hi(pv.x);         \
                    ps[n][2] += bf16lo(pv.y); ps[n][3] += bf16hi(pv.y);         \
                }                                                               \
                if (e + grp < nde[n]) {                                         \
                    sn = sn < (unsigned)N ? sn : 0u;                            \
                    uint2 nv = *((const uint2*)((SRC) + ((size_t)sn << 6)) + q);\
                    ns[n][0] += bf16lo(nv.x); ns[n][1] += bf16hi(nv.x);         \
                    ns[n][2] += bf16lo(nv.y); ns[n][3] += bf16hi(nv.y);         \
                }                                                               \
            }                                                                   \
        }                                                                       \
        _Pragma("unroll")                                                       \
        for (int n = 0; n < 4; ++n) {                                           \
            _Pragma("unroll")                                                   \
            for (int r = 0; r < 4; ++r) {                                       \
                ps[n][r] += __shfl_xor(ps[n][r], 16);                           \
                ps[n][r] += __shfl_xor(ps[n][r], 32);                           \
                ns[n][r] += __shfl_xor(ns[n][r], 16);                           \
                ns[n][r] += __shfl_xor(ns[n][r], 32);                           \
            }                                                                   \
            float invp = 1.f / fmaxf((float)pd[n], 1.f);                        \
            float invn = 1.f / fmaxf((float)nd[n], 1.f);                        \
            short* lrow = &lds[(g * 4 + n) * 132];                              \
            if (grp == 0) {                                                     \
                uint2 ow;                                                       \
                ow.x = pack2(ps[n][0] * invp, ps[n][1] * invp);                 \
                ow.y = pack2(ps[n][2] * invp, ps[n][3] * invp);                 \
                *(uint2*)(lrow + 4 * q) = ow;                                   \
            } else if (grp == 1) {                                              \
                uint2 ow;                                                       \
                ow.x = pack2(ns[n][0] * invn, ns[n][1] * invn);                 \
                ow.y = pack2(ns[n][2] * invn, ns[n][3] * invn);                 \
                *(uint2*)(lrow + 64 + 4 * q) = ow;                              \
            }                                                                   \
        }                                                                       \
    }

// ---------------------------------------------------------------------------
// Layer 1: gather(xb) -> LDS means -> z1b = tanh([ap,x]@Wp1 | [an,x]@Wn1)
// ---------------------------------------------------------------------------
__global__ __launch_bounds__(256, 4) void pg_layer1(
    const __hip_bfloat16* __restrict__ xb,
    const int* __restrict__ plist, const int* __restrict__ nlist,
    const int* __restrict__ pcur, const int* __restrict__ ncur,
    const float* __restrict__ Wp, const float* __restrict__ bp,
    const float* __restrict__ Wn, const float* __restrict__ bn,
    __hip_bfloat16* __restrict__ z1b, int N)
{
    __shared__ short smem[4][16 * 132];
    int tid = threadIdx.x;
    int w = tid >> 6, lane = tid & 63;
    int grp = lane >> 4, q = lane & 15;
    short* lds = smem[w];
    int base = blockIdx.x * 64 + w * 16;

    GATHER_16NODES(xb)

    __builtin_amdgcn_sched_barrier(0);

    // ---- gemm phase ----
    int q8 = lane >> 4, c = lane & 15;
    bf16x8 B[2][4][2];
    #pragma unroll
    for (int kt = 0; kt < 4; ++kt)
        #pragma unroll
        for (int ct = 0; ct < 2; ++ct) {
            B[0][kt][ct] = wfrag(Wp, 32, kt, ct, q8, c);
            B[1][kt][ct] = wfrag(Wn, 32, kt, ct, q8, c);
        }
    float bias[2][2];
    #pragma unroll
    for (int ct = 0; ct < 2; ++ct) {
        bias[0][ct] = bp[ct * 16 + c];
        bias[1][ct] = bn[ct * 16 + c];
    }
    int i = min(base + c, N - 1);
    const __hip_bfloat16* xrow = xb + ((size_t)i << 6);
    const short* lrow = &lds[c * 132];
    bf16x8 aA0 = lfrag(lrow, 0, q8);
    bf16x8 aA1 = lfrag(lrow, 32, q8);
    bf16x8 aA2 = lfrag(lrow, 64, q8);
    bf16x8 aA3 = lfrag(lrow, 96, q8);
    bf16x8 aX0 = afrag_bf16(xrow, 0, q8);
    bf16x8 aX1 = afrag_bf16(xrow, 32, q8);
    f32x4 acc[2][2];
    #pragma unroll
    for (int ct = 0; ct < 2; ++ct) {
        f32x4 a = {0.f, 0.f, 0.f, 0.f};
        a = MFMA(aA0, B[0][0][ct], a);
        a = MFMA(aA1, B[0][1][ct], a);
        a = MFMA(aX0, B[0][2][ct], a);
        a = MFMA(aX1, B[0][3][ct], a);
        acc[0][ct] = a;
        f32x4 b = {0.f, 0.f, 0.f, 0.f};
        b = MFMA(aA2, B[1][0][ct], b);
        b = MFMA(aA3, B[1][1][ct], b);
        b = MFMA(aX0, B[1][2][ct], b);
        b = MFMA(aX1, B[1][3][ct], b);
        acc[1][ct] = b;
    }
    #pragma unroll
    for (int h = 0; h < 2; ++h)
        #pragma unroll
        for (int ct = 0; ct < 2; ++ct)
            #pragma unroll
            for (int r = 0; r < 4; ++r) {
                int row = base + q8 * 4 + r;
                if (row < N)
                    z1b[(size_t)row * 64 + h * 32 + ct * 16 + c] =
                        __float2bfloat16(tanhf(acc[h][ct][r] + bias[h][ct]));
            }
}

// ---------------------------------------------------------------------------
// Layer 2: gather(z1b) -> LDS means -> z2b = tanh([windows, z1]@Wp2|Wn2)
// z2b written bf16 into ws z2b region (stride 128).
// ---------------------------------------------------------------------------
__global__ __launch_bounds__(256, 4) void pg_layer2(
    const __hip_bfloat16* __restrict__ z1b,
    const int* __restrict__ plist, const int* __restrict__ nlist,
    const int* __restrict__ pcur, const int* __restrict__ ncur,
    const float* __restrict__ Wp2, const float* __restrict__ bp2,
    const float* __restrict__ Wn2, const float* __restrict__ bn2,
    __hip_bfloat16* __restrict__ z2b, int N)
{
    __shared__ short smem[4][16 * 132];
    int tid = threadIdx.x;
    int w = tid >> 6, lane = tid & 63;
    int grp = lane >> 4, q = lane & 15;
    short* lds = smem[w];
    int base = blockIdx.x * 64 + w * 16;

    GATHER_16NODES(z1b)

    __builtin_amdgcn_sched_barrier(0);

    // ---- gemm phase ----
    int q8 = lane >> 4, c = lane & 15;
    bf16x8 B[2][3][2];
    #pragma unroll
    for (int kt = 0; kt < 3; ++kt)
        #pragma unroll
        for (int ct = 0; ct < 2; ++ct) {
            B[0][kt][ct] = wfrag(Wp2, 32, kt, ct, q8, c);
            B[1][kt][ct] = wfrag(Wn2, 32, kt, ct, q8, c);
        }
    float bias[2][2];
    #pragma unroll
    for (int ct = 0; ct < 2; ++ct) {
        bias[0][ct] = bp2[ct * 16 + c];
        bias[1][ct] = bn2[ct * 16 + c];
    }
    int i = min(base + c, N - 1);
    const __hip_bfloat16* zrow = z1b + ((size_t)i << 6);
    const short* lrow = &lds[c * 132];
    bf16x8 ap0 = lfrag(lrow, 0, q8);    // agg_pos(xp)
    bf16x8 ap1 = lfrag(lrow, 96, q8);   // agg_neg(xn)
    bf16x8 an0 = lfrag(lrow, 32, q8);   // agg_pos(xn)
    bf16x8 an1 = lfrag(lrow, 64, q8);   // agg_neg(xp)
    bf16x8 az0 = afrag_bf16(zrow, 0, q8);
    bf16x8 az1 = afrag_bf16(zrow, 32, q8);
    f32x4 acc[2][2];
    #pragma unroll
    for (int ct = 0; ct < 2; ++ct) {
        f32x4 a = {0.f, 0.f, 0.f, 0.f};
        a = MFMA(ap0, B[0][0][ct], a);
        a = MFMA(ap1, B[0][1][ct], a);
        a = MFMA(az0, B[0][2][ct], a);
        acc[0][ct] = a;
        f32x4 b = {0.f, 0.f, 0.f, 0.f};
        b = MFMA(an0, B[1][0][ct], b);
        b = MFMA(an1, B[1][1][ct], b);
        b = MFMA(az1, B[1][2][ct], b);
        acc[1][ct] = b;
    }
    #pragma unroll
    for (int h = 0; h < 2; ++h)
        #pragma unroll
        for (int ct = 0; ct < 2; ++ct)
            #pragma unroll
            for (int r = 0; r < 4; ++r) {
                int row = base + q8 * 4 + r;
                if (row < N)
                    z2b[(size_t)row * 128 + h * 32 + ct * 16 + c] =
                        __float2bfloat16(tanhf(acc[h][ct][r] + bias[h][ct]));
            }
}

// ---------------------------------------------------------------------------
// MLP head (MFMA chain): z = tanh(z2@Ww+bw) -> out; BN/ReLU x2; dot Wm3 ->
// sigmoid prob. z2b read bf16 (stride 128). LDS transpose between stages.
// ---------------------------------------------------------------------------
__global__ __launch_bounds__(256, 2) void pg_mlp(
    float* out, const __hip_bfloat16* __restrict__ z2b,
    const float* __restrict__ Ww,  const float* __restrict__ bw,
    const float* __restrict__ Wm1, const float* __restrict__ bm1,
    const float* __restrict__ g1,  const float* __restrict__ be1,
    const float* __restrict__ rm1, const float* __restrict__ rv1,
    const float* __restrict__ Wm2, const float* __restrict__ bm2,
    const float* __restrict__ g2,  const float* __restrict__ be2,
    const float* __restrict__ rm2, const float* __restrict__ rv2,
    const float* __restrict__ Wm3, const float* __restrict__ bm3,
    int N, int nwv)
{
    __shared__ float xpos[4][16][68];
    int tid = threadIdx.x;
    int w = tid >> 6, lane = tid & 63;
    int q = lane >> 4, c = lane & 15;
    float (*lx)[68] = xpos[w];

    bf16x8 Bw[2][4], B1[2][4], B2[2][4];
    #pragma unroll
    for (int kt = 0; kt < 2; ++kt)
        #pragma unroll
        for (int ct = 0; ct < 4; ++ct) {
            Bw[kt][ct] = wfrag(Ww,  64, kt, ct, q, c);
            B1[kt][ct] = wfrag(Wm1, 64, kt, ct, q, c);
            B2[kt][ct] = wfrag(Wm2, 64, kt, ct, q, c);
        }
    float bwv[4], s1[4], o1[4], s2[4], o2[4], w3[4];
    #pragma unroll
    for (int ct = 0; ct < 4; ++ct) {
        int cc = ct * 16 + c;
        bwv[ct] = bw[cc];
        float a = g1[cc] * rsqrtf(rv1[cc] + 1e-5f);
        s1[ct] = a; o1[ct] = (bm1[cc] - rm1[cc]) * a + be1[cc];
        float b = g2[cc] * rsqrtf(rv2[cc] + 1e-5f);
        s2[ct] = b; o2[ct] = (bm2[cc] - rm2[cc]) * b + be2[cc];
        w3[ct] = Wm3[cc];
    }
    float b3 = bm3[0];

    int ntiles = (N + 15) >> 4;
    #pragma unroll 1
    for (int t = blockIdx.x * 4 + w; t < ntiles; t += nwv) {
        int i = min(t * 16 + c, N - 1);
        const __hip_bfloat16* zrow = z2b + ((size_t)i << 7);
        bf16x8 a0 = afrag_bf16(zrow, 0, q);
        bf16x8 a1 = afrag_bf16(zrow, 32, q);
        f32x4 acc[4];

        // ---- Ww -> tanh -> final z (global + LDS) ----
        #pragma unroll
        for (int ct = 0; ct < 4; ++ct) {
            f32x4 a = {0.f, 0.f, 0.f, 0.f};
            a = MFMA(a0, Bw[0][ct], a);
            a = MFMA(a1, Bw[1][ct], a);
            acc[ct] = a;
        }
        #pragma unroll
        for (int ct = 0; ct < 4; ++ct)
            #pragma unroll
            for (int r = 0; r < 4; ++r) {
                int row = t * 16 + q * 4 + r;
                float v = tanhf(acc[ct][r] + bwv[ct]);
                if (row < N) out[(size_t)row * 64 + ct * 16 + c] = v;
                lx[q * 4 + r][ct * 16 + c] = v;
            }
        {
            const float* pr = &lx[c][0];
            float tb[8];
            *(float4*)tb       = *(const float4*)(pr + q * 8);
            *(float4*)(tb + 4) = *(const float4*)(pr + q * 8 + 4);
            a0 = packbf8(tb);
            *(float4*)tb       = *(const float4*)(pr + 32 + q * 8);
            *(float4*)(tb + 4) = *(const float4*)(pr + 32 + q * 8 + 4);
            a1 = packbf8(tb);
        }

        // ---- Wm1 -> BN -> ReLU ----
        #pragma unroll
        for (int ct = 0; ct < 4; ++ct) {
            f32x4 a = {0.f, 0.f, 0.f, 0.f};
            a = MFMA(a0, B1[0][ct], a);
            a = MFMA(a1, B1[1][ct], a);
            acc[ct] = a;
        }
        #pragma unroll
        for (int ct = 0; ct < 4; ++ct)
            #pragma unroll
            for (int r = 0; r < 4; ++r)
                lx[q * 4 + r][ct * 16 + c] = fmaxf(acc[ct][r] * s1[ct] + o1[ct], 0.f);
        {
            const float* pr = &lx[c][0];
            float tb[8];
            *(float4*)tb       = *(const float4*)(pr + q * 8);
            *(float4*)(tb + 4) = *(const float4*)(pr + q * 8 + 4);
            a0 = packbf8(tb);
            *(float4*)tb       = *(const float4*)(pr + 32 + q * 8);
            *(float4*)(tb + 4) = *(const float4*)(pr + 32 + q * 8 + 4);
            a1 = packbf8(tb);
        }

        // ---- Wm2 -> BN -> ReLU -> dot Wm3 -> sigmoid ----
        #pragma unroll
        for (int ct = 0; ct < 4; ++ct) {
            f32x4 a = {0.f, 0.f, 0.f, 0.f};
            a = MFMA(a0, B2[0][ct], a);
            a = MFMA(a1, B2[1][ct], a);
            acc[ct] = a;
        }
        float tr[4];
        #pragma unroll
        for (int r = 0; r < 4; ++r) {
            float hs = 0.f;
            #pragma unroll
            for (int ct = 0; ct < 4; ++ct) {
                float h2 = fmaxf(acc[ct][r] * s2[ct] + o2[ct], 0.f);
                hs = fmaf(h2, w3[ct], hs);
            }
            tr[r] = hs;
        }
        #pragma unroll
        for (int m = 1; m < 16; m <<= 1)
            #pragma unroll
            for (int r = 0; r < 4; ++r) tr[r] += __shfl_xor(tr[r], m, 16);
        if (c == 0) {
            #pragma unroll
            for (int r = 0; r < 4; ++r) {
                int row = t * 16 + q * 4 + r;
                if (row < N)
                    out[(size_t)N * 64 + row] = 1.f / (1.f + expf(-(tr[r] + b3)));
            }
        }
    }
}

extern "C" void kernel_launch(void* const* d_in, const int* in_sizes, int n_in,
                              void* d_out, int out_size, void* d_ws, size_t ws_size,
                              hipStream_t stream) {
    const float* x   = (const float*)d_in[0];
    const int*   ei  = (const int*)  d_in[1];
    const float* Wp1 = (const float*)d_in[2];
    const float* bp1 = (const float*)d_in[3];
    const float* Wn1 = (const float*)d_in[4];
    const float* bn1 = (const float*)d_in[5];
    const float* Wp2 = (const float*)d_in[6];
    const float* bp2 = (const float*)d_in[7];
    const float* Wn2 = (const float*)d_in[8];
    const float* bn2 = (const float*)d_in[9];
    const float* Ww  = (const float*)d_in[10];
    const float* bw  = (const float*)d_in[11];
    const float* Wm1 = (const float*)d_in[12];
    const float* bm1 = (const float*)d_in[13];
    const float* g1  = (const float*)d_in[14];
    const float* be1 = (const float*)d_in[15];
    const float* rm1 = (const float*)d_in[16];
    const float* rv1 = (const float*)d_in[17];
    const float* Wm2 = (const float*)d_in[18];
    const float* bm2 = (const float*)d_in[19];
    const float* g2  = (const float*)d_in[20];
    const float* be2 = (const float*)d_in[21];
    const float* rm2 = (const float*)d_in[22];
    const float* rv2 = (const float*)d_in[23];
    const float* Wm3 = (const float*)d_in[24];
    const float* bm3 = (const float*)d_in[25];
    float* out = (float*)d_out;

    int N = in_sizes[0] / 64;
    int E = in_sizes[1] / 3;

    // ws layout (52.0 MB for N=100K): plist | nlist | pcur | ncur | z2b(bf16 N x 128)
    int* plist = (int*)d_ws;
    int* nlist = plist + (size_t)N * CAP;
    int* pcur  = nlist + (size_t)N * CAP;
    int* ncur  = pcur + N;
    __hip_bfloat16* z2b = (__hip_bfloat16*)(ncur + N);

    // d_out z region staging: z1b = first half, xb = second half (dead by mlp).
    __hip_bfloat16* z1b = (__hip_bfloat16*)out;                              // N x 64
    __hip_bfloat16* xb  = (__hip_bfloat16*)((char*)d_out + (size_t)N * 128); // N x 64

    hipMemsetAsync(pcur, 0, 2 * (size_t)N * sizeof(int), stream);

    int buildBlocks = (E + 1023) / 1024;
    int castBlocks  = (N * 64 / 4 + 255) / 256;
    pg_build_cast<<<buildBlocks + castBlocks, 256, 0, stream>>>(
        ei, plist, nlist, pcur, ncur, E, buildBlocks, x, xb, N * 64);

    int nb = (N + 63) / 64;
    pg_layer1<<<nb, 256, 0, stream>>>(xb, plist, nlist, pcur, ncur,
                                      Wp1, bp1, Wn1, bn1, z1b, N);
    pg_layer2<<<nb, 256, 0, stream>>>(z1b, plist, nlist, pcur, ncur,
                                      Wp2, bp2, Wn2, bn2, z2b, N);
    const int gb = 512, nwv = gb * 4;
    pg_mlp<<<gb, 256, 0, stream>>>(out, z2b, Ww, bw,
                                   Wm1, bm1, g1, be1, rm1, rv1,
                                   Wm2, bm2, g2, be2, rm2, rv2,
                                   Wm3, bm3, N, nwv);
}

// Round 11
// 253.489 us; speedup vs baseline: 1.0557x; 1.0557x over previous
//
#include <hip/hip_runtime.h>
#include <hip/hip_bf16.h>

#define CAP 32   // padded adjacency slots per node per sign (Poisson λ≈6.25)

typedef __attribute__((ext_vector_type(8))) short bf16x8;
typedef __attribute__((ext_vector_type(4))) float f32x4;

#define MFMA(a, b, c) __builtin_amdgcn_mfma_f32_16x16x32_bf16(a, b, c, 0, 0, 0)

__device__ __forceinline__ unsigned short bf16rn(float f) {
    unsigned u = __builtin_bit_cast(unsigned, f);
    u += 0x7fffu + ((u >> 16) & 1u);
    return (unsigned short)(u >> 16);
}
__device__ __forceinline__ float bf16lo(unsigned u) {
    return __builtin_bit_cast(float, u << 16);
}
__device__ __forceinline__ float bf16hi(unsigned u) {
    return __builtin_bit_cast(float, u & 0xffff0000u);
}
__device__ __forceinline__ unsigned pack2(float a, float b) {
    return (unsigned)bf16rn(a) | ((unsigned)bf16rn(b) << 16);
}
__device__ __forceinline__ bf16x8 packbf8(const float* p) {
    bf16x8 r;
    #pragma unroll
    for (int j = 0; j < 8; ++j) r[j] = (short)bf16rn(p[j]);
    return r;
}

// B-frag from row-major f32 W[K][NN]: elem j = W[kt*32 + q*8 + j][ct*16 + c]
__device__ __forceinline__ bf16x8 wfrag(const float* __restrict__ W, int NN,
                                        int kt, int ct, int q, int c) {
    const float* base = W + (kt * 32 + q * 8) * NN + ct * 16 + c;
    float t[8];
    #pragma unroll
    for (int j = 0; j < 8; ++j) t[j] = base[j * NN];
    return packbf8(t);
}

// A-frag: row-major bf16 source, contiguous 32-col window starting at cw
__device__ __forceinline__ bf16x8 afrag_bf16(const __hip_bfloat16* row, int cw, int q) {
    return *(const bf16x8*)((const short*)row + cw + q * 8);
}

// ---------------------------------------------------------------------------
// Fused: adjacency build (4 edges/thread) + x->bf16 cast.
// ---------------------------------------------------------------------------
__global__ __launch_bounds__(256) void pg_build_cast(
    const int* __restrict__ ei,
    int* __restrict__ plist, int* __restrict__ nlist,
    int* __restrict__ pcur, int* __restrict__ ncur, int E, int buildBlocks,
    const float* __restrict__ x, __hip_bfloat16* __restrict__ xb, int nx)
{
    int b = blockIdx.x;
    if (b >= buildBlocks) {
        int i = ((b - buildBlocks) * 256 + threadIdx.x) * 4;
        if (i < nx) {
            float4 v = *(const float4*)(x + i);
            ushort4 o;
            o.x = bf16rn(v.x); o.y = bf16rn(v.y);
            o.z = bf16rn(v.z); o.w = bf16rn(v.w);
            *(ushort4*)((unsigned short*)xb + i) = o;
        }
        return;
    }
    int e0 = (b * 256 + threadIdx.x) * 4;
    int s[4], d[4], sg[4];
    bool ok[4];
    #pragma unroll
    for (int k = 0; k < 4; ++k) {
        int e = e0 + k;
        ok[k] = (e < E);
        int ee = ok[k] ? e : 0;
        s[k]  = ei[3 * ee + 0];
        d[k]  = ei[3 * ee + 1];
        sg[k] = ei[3 * ee + 2];
    }
    int slot[4];
    int* dstl[4];
    #pragma unroll
    for (int k = 0; k < 4; ++k) {
        int* cur = (sg[k] > 0) ? pcur : ncur;
        dstl[k]  = ((sg[k] > 0) ? plist : nlist) + (size_t)d[k] * CAP;
        slot[k]  = ok[k] ? atomicAdd(cur + d[k], 1) : CAP;
    }
    #pragma unroll
    for (int k = 0; k < 4; ++k)
        if (slot[k] < CAP) dstl[k][slot[k]] = s[k];
}

// ---------------------------------------------------------------------------
// Gather: per node, pos/neg mean of bf16 src rows -> packed bf16 agg row
//   agg[i] = [ pmean(64) | nmean(64) ]
// 4 slots per VMEM instruction (grp=lane>>4, dwordx2 each), EXEC-MASKED so
// dummy slots issue no line transactions. High occupancy (6 blocks/CU).
// ---------------------------------------------------------------------------
__global__ __launch_bounds__(256, 6) void pg_gather(
    const __hip_bfloat16* __restrict__ src,
    const int* __restrict__ plist, const int* __restrict__ nlist,
    const int* __restrict__ pcur, const int* __restrict__ ncur,
    __hip_bfloat16* __restrict__ agg, int N)
{
    int tid = threadIdx.x;
    int w = tid >> 6, lane = tid & 63;
    int grp = lane >> 4;      // slot offset within the 4-slot batch
    int q   = lane & 15;      // col-quad: cols 4q..4q+3

    #pragma unroll 1
    for (int g = 0; g < 4; ++g) {
        int i0 = blockIdx.x * 64 + w * 16 + g * 4;
        int pd[4], nd[4], pde[4], nde[4], pl[4], nl[4];
        #pragma unroll
        for (int n = 0; n < 4; ++n) {
            int i = min(i0 + n, N - 1);
            pd[n] = __builtin_amdgcn_readfirstlane(pcur[i]);
            nd[n] = __builtin_amdgcn_readfirstlane(ncur[i]);
            pde[n] = min(pd[n], CAP);
            nde[n] = min(nd[n], CAP);
            pl[n] = plist[(size_t)i * CAP + (lane & 31)];
            nl[n] = nlist[(size_t)i * CAP + (lane & 31)];
        }
        int maxd = 0;
        #pragma unroll
        for (int n = 0; n < 4; ++n) maxd = max(maxd, max(pde[n], nde[n]));

        float ps[4][4], ns[4][4];
        #pragma unroll
        for (int n = 0; n < 4; ++n)
            #pragma unroll
            for (int r = 0; r < 4; ++r) { ps[n][r] = 0.f; ns[n][r] = 0.f; }

        #pragma unroll 1
        for (int e = 0; e < maxd; e += 4) {
            #pragma unroll
            for (int n = 0; n < 4; ++n) {
                int p0 = __builtin_amdgcn_readlane(pl[n], (e + 0) < pde[n] ? e + 0 : 0);
                int p1 = __builtin_amdgcn_readlane(pl[n], (e + 1) < pde[n] ? e + 1 : 0);
                int p2 = __builtin_amdgcn_readlane(pl[n], (e + 2) < pde[n] ? e + 2 : 0);
                int p3 = __builtin_amdgcn_readlane(pl[n], (e + 3) < pde[n] ? e + 3 : 0);
                int m0 = __builtin_amdgcn_readlane(nl[n], (e + 0) < nde[n] ? e + 0 : 0);
                int m1 = __builtin_amdgcn_readlane(nl[n], (e + 1) < nde[n] ? e + 1 : 0);
                int m2 = __builtin_amdgcn_readlane(nl[n], (e + 2) < nde[n] ? e + 2 : 0);
                int m3 = __builtin_amdgcn_readlane(nl[n], (e + 3) < nde[n] ? e + 3 : 0);
                unsigned sp = (unsigned)(grp == 0 ? p0 : grp == 1 ? p1 : grp == 2 ? p2 : p3);
                unsigned sn = (unsigned)(grp == 0 ? m0 : grp == 1 ? m1 : grp == 2 ? m2 : m3);
                if (e + grp < pde[n]) {        // exec-masked: no dummy txns
                    sp = sp < (unsigned)N ? sp : 0u;
                    uint2 pv = *((const uint2*)(src + ((size_t)sp << 6)) + q);
                    ps[n][0] += bf16lo(pv.x); ps[n][1] += bf16hi(pv.x);
                    ps[n][2] += bf16lo(pv.y); ps[n][3] += bf16hi(pv.y);
                }
                if (e + grp < nde[n]) {
                    sn = sn < (unsigned)N ? sn : 0u;
                    uint2 nv = *((const uint2*)(src + ((size_t)sn << 6)) + q);
                    ns[n][0] += bf16lo(nv.x); ns[n][1] += bf16hi(nv.x);
                    ns[n][2] += bf16lo(nv.y); ns[n][3] += bf16hi(nv.y);
                }
            }
        }
        #pragma unroll
        for (int n = 0; n < 4; ++n) {
            #pragma unroll
            for (int r = 0; r < 4; ++r) {
                ps[n][r] += __shfl_xor(ps[n][r], 16);
                ps[n][r] += __shfl_xor(ps[n][r], 32);
                ns[n][r] += __shfl_xor(ns[n][r], 16);
                ns[n][r] += __shfl_xor(ns[n][r], 32);
            }
            int i = i0 + n;
            if (i < N) {
                float invp = 1.f / fmaxf((float)pd[n], 1.f);
                float invn = 1.f / fmaxf((float)nd[n], 1.f);
                uint2* arow = (uint2*)(agg + ((size_t)i << 7));
                if (grp == 0) {
                    uint2 ow;
                    ow.x = pack2(ps[n][0] * invp, ps[n][1] * invp);
                    ow.y = pack2(ps[n][2] * invp, ps[n][3] * invp);
                    arow[q] = ow;
                } else if (grp == 1) {
                    uint2 ow;
                    ow.x = pack2(ns[n][0] * invn, ns[n][1] * invn);
                    ow.y = pack2(ns[n][2] * invn, ns[n][3] * invn);
                    arow[16 + q] = ow;
                }
            }
        }
    }
}

// ---------------------------------------------------------------------------
// GEMM1 (MFMA): z1b = tanh([ap,x]@Wp1 | [an,x]@Wn1), bf16 in / bf16 out.
// ---------------------------------------------------------------------------
__global__ __launch_bounds__(256, 3) void pg_gemm1(
    const __hip_bfloat16* __restrict__ xb, const __hip_bfloat16* __restrict__ agg,
    const float* __restrict__ Wp, const float* __restrict__ bp,
    const float* __restrict__ Wn, const float* __restrict__ bn,
    __hip_bfloat16* __restrict__ z1b, int N, int nwv)
{
    int tid = threadIdx.x;
    int w = tid >> 6, lane = tid & 63;
    int q = lane >> 4, c = lane & 15;

    bf16x8 B[2][4][2];
    #pragma unroll
    for (int kt = 0; kt < 4; ++kt)
        #pragma unroll
        for (int ct = 0; ct < 2; ++ct) {
            B[0][kt][ct] = wfrag(Wp, 32, kt, ct, q, c);
            B[1][kt][ct] = wfrag(Wn, 32, kt, ct, q, c);
        }
    float bias[2][2];
    #pragma unroll
    for (int ct = 0; ct < 2; ++ct) {
        bias[0][ct] = bp[ct * 16 + c];
        bias[1][ct] = bn[ct * 16 + c];
    }

    int ntiles = (N + 15) >> 4;
    #pragma unroll 1
    for (int t = blockIdx.x * 4 + w; t < ntiles; t += nwv) {
        int i = min(t * 16 + c, N - 1);
        const __hip_bfloat16* arow = agg + ((size_t)i << 7);
        const __hip_bfloat16* xrow = xb + ((size_t)i << 6);
        bf16x8 aA0 = afrag_bf16(arow, 0, q);
        bf16x8 aA1 = afrag_bf16(arow, 32, q);
        bf16x8 aA2 = afrag_bf16(arow, 64, q);
        bf16x8 aA3 = afrag_bf16(arow, 96, q);
        bf16x8 aX0 = afrag_bf16(xrow, 0, q);
        bf16x8 aX1 = afrag_bf16(xrow, 32, q);
        f32x4 acc[2][2];
        #pragma unroll
        for (int ct = 0; ct < 2; ++ct) {
            f32x4 a = {0.f, 0.f, 0.f, 0.f};
            a = MFMA(aA0, B[0][0][ct], a);
            a = MFMA(aA1, B[0][1][ct], a);
            a = MFMA(aX0, B[0][2][ct], a);
            a = MFMA(aX1, B[0][3][ct], a);
            acc[0][ct] = a;
            f32x4 b = {0.f, 0.f, 0.f, 0.f};
            b = MFMA(aA2, B[1][0][ct], b);
            b = MFMA(aA3, B[1][1][ct], b);
            b = MFMA(aX0, B[1][2][ct], b);
            b = MFMA(aX1, B[1][3][ct], b);
            acc[1][ct] = b;
        }
        #pragma unroll
        for (int h = 0; h < 2; ++h)
            #pragma unroll
            for (int ct = 0; ct < 2; ++ct)
                #pragma unroll
                for (int r = 0; r < 4; ++r) {
                    int row = t * 16 + q * 4 + r;
                    if (row < N)
                        z1b[(size_t)row * 64 + h * 32 + ct * 16 + c] =
                            __float2bfloat16(tanhf(acc[h][ct][r] + bias[h][ct]));
                }
    }
}

// ---------------------------------------------------------------------------
// GEMM2 (MFMA): z2 = tanh([agg-windows, z1]@Wp2 | ...@Wn2).
// z2b written bf16 into agg region cols 0..63 (stride 128) -> row-local, safe.
// ---------------------------------------------------------------------------
__global__ __launch_bounds__(256, 3) void pg_gemm2(
    const __hip_bfloat16* __restrict__ z1b, __hip_bfloat16* agg,
    const float* __restrict__ Wp2, const float* __restrict__ bp2,
    const float* __restrict__ Wn2, const float* __restrict__ bn2,
    int N, int nwv)
{
    int tid = threadIdx.x;
    int w = tid >> 6, lane = tid & 63;
    int q = lane >> 4, c = lane & 15;

    bf16x8 B[2][3][2];
    #pragma unroll
    for (int kt = 0; kt < 3; ++kt)
        #pragma unroll
        for (int ct = 0; ct < 2; ++ct) {
            B[0][kt][ct] = wfrag(Wp2, 32, kt, ct, q, c);
            B[1][kt][ct] = wfrag(Wn2, 32, kt, ct, q, c);
        }
    float bias[2][2];
    #pragma unroll
    for (int ct = 0; ct < 2; ++ct) {
        bias[0][ct] = bp2[ct * 16 + c];
        bias[1][ct] = bn2[ct * 16 + c];
    }

    int ntiles = (N + 15) >> 4;
    #pragma unroll 1
    for (int t = blockIdx.x * 4 + w; t < ntiles; t += nwv) {
        int i = min(t * 16 + c, N - 1);
        const __hip_bfloat16* arow = agg + ((size_t)i << 7);
        const __hip_bfloat16* zrow = z1b + ((size_t)i << 6);
        bf16x8 ap0 = afrag_bf16(arow, 0, q);
        bf16x8 ap1 = afrag_bf16(arow, 96, q);
        bf16x8 an0 = afrag_bf16(arow, 32, q);
        bf16x8 an1 = afrag_bf16(arow, 64, q);
        bf16x8 az0 = afrag_bf16(zrow, 0, q);
        bf16x8 az1 = afrag_bf16(zrow, 32, q);
        f32x4 acc[2][2];
        #pragma unroll
        for (int ct = 0; ct < 2; ++ct) {
            f32x4 a = {0.f, 0.f, 0.f, 0.f};
            a = MFMA(ap0, B[0][0][ct], a);
            a = MFMA(ap1, B[0][1][ct], a);
            a = MFMA(az0, B[0][2][ct], a);
            acc[0][ct] = a;
            f32x4 b = {0.f, 0.f, 0.f, 0.f};
            b = MFMA(an0, B[1][0][ct], b);
            b = MFMA(an1, B[1][1][ct], b);
            b = MFMA(az1, B[1][2][ct], b);
            acc[1][ct] = b;
        }
        #pragma unroll
        for (int h = 0; h < 2; ++h)
            #pragma unroll
            for (int ct = 0; ct < 2; ++ct)
                #pragma unroll
                for (int r = 0; r < 4; ++r) {
                    int row = t * 16 + q * 4 + r;
                    if (row < N)
                        agg[(size_t)row * 128 + h * 32 + ct * 16 + c] =
                            __float2bfloat16(tanhf(acc[h][ct][r] + bias[h][ct]));
                }
    }
}

// ---------------------------------------------------------------------------
// MLP head (MFMA chain): z = tanh(z2@Ww+bw) -> out; BN/ReLU x2; dot Wm3 ->
// sigmoid prob. z2b read bf16 (stride 128). LDS transpose between stages.
// ---------------------------------------------------------------------------
__global__ __launch_bounds__(256, 2) void pg_mlp(
    float* out, const __hip_bfloat16* __restrict__ z2b,
    const float* __restrict__ Ww,  const float* __restrict__ bw,
    const float* __restrict__ Wm1, const float* __restrict__ bm1,
    const float* __restrict__ g1,  const float* __restrict__ be1,
    const float* __restrict__ rm1, const float* __restrict__ rv1,
    const float* __restrict__ Wm2, const float* __restrict__ bm2,
    const float* __restrict__ g2,  const float* __restrict__ be2,
    const float* __restrict__ rm2, const float* __restrict__ rv2,
    const float* __restrict__ Wm3, const float* __restrict__ bm3,
    int N, int nwv)
{
    __shared__ float xpos[4][16][68];
    int tid = threadIdx.x;
    int w = tid >> 6, lane = tid & 63;
    int q = lane >> 4, c = lane & 15;
    float (*lx)[68] = xpos[w];

    bf16x8 Bw[2][4], B1[2][4], B2[2][4];
    #pragma unroll
    for (int kt = 0; kt < 2; ++kt)
        #pragma unroll
        for (int ct = 0; ct < 4; ++ct) {
            Bw[kt][ct] = wfrag(Ww,  64, kt, ct, q, c);
            B1[kt][ct] = wfrag(Wm1, 64, kt, ct, q, c);
            B2[kt][ct] = wfrag(Wm2, 64, kt, ct, q, c);
        }
    float bwv[4], s1[4], o1[4], s2[4], o2[4], w3[4];
    #pragma unroll
    for (int ct = 0; ct < 4; ++ct) {
        int cc = ct * 16 + c;
        bwv[ct] = bw[cc];
        float a = g1[cc] * rsqrtf(rv1[cc] + 1e-5f);
        s1[ct] = a; o1[ct] = (bm1[cc] - rm1[cc]) * a + be1[cc];
        float b = g2[cc] * rsqrtf(rv2[cc] + 1e-5f);
        s2[ct] = b; o2[ct] = (bm2[cc] - rm2[cc]) * b + be2[cc];
        w3[ct] = Wm3[cc];
    }
    float b3 = bm3[0];

    int ntiles = (N + 15) >> 4;
    #pragma unroll 1
    for (int t = blockIdx.x * 4 + w; t < ntiles; t += nwv) {
        int i = min(t * 16 + c, N - 1);
        const __hip_bfloat16* zrow = z2b + ((size_t)i << 7);
        bf16x8 a0 = afrag_bf16(zrow, 0, q);
        bf16x8 a1 = afrag_bf16(zrow, 32, q);
        f32x4 acc[4];

        // ---- Ww -> tanh -> final z (global + LDS) ----
        #pragma unroll
        for (int ct = 0; ct < 4; ++ct) {
            f32x4 a = {0.f, 0.f, 0.f, 0.f};
            a = MFMA(a0, Bw[0][ct], a);
            a = MFMA(a1, Bw[1][ct], a);
            acc[ct] = a;
        }
        #pragma unroll
        for (int ct = 0; ct < 4; ++ct)
            #pragma unroll
            for (int r = 0; r < 4; ++r) {
                int row = t * 16 + q * 4 + r;
                float v = tanhf(acc[ct][r] + bwv[ct]);
                if (row < N) out[(size_t)row * 64 + ct * 16 + c] = v;
                lx[q * 4 + r][ct * 16 + c] = v;
            }
        {
            const float* pr = &lx[c][0];
            float tb[8];
            *(float4*)tb       = *(const float4*)(pr + q * 8);
            *(float4*)(tb + 4) = *(const float4*)(pr + q * 8 + 4);
            a0 = packbf8(tb);
            *(float4*)tb       = *(const float4*)(pr + 32 + q * 8);
            *(float4*)(tb + 4) = *(const float4*)(pr + 32 + q * 8 + 4);
            a1 = packbf8(tb);
        }

        // ---- Wm1 -> BN -> ReLU ----
        #pragma unroll
        for (int ct = 0; ct < 4; ++ct) {
            f32x4 a = {0.f, 0.f, 0.f, 0.f};
            a = MFMA(a0, B1[0][ct], a);
            a = MFMA(a1, B1[1][ct], a);
            acc[ct] = a;
        }
        #pragma unroll
        for (int ct = 0; ct < 4; ++ct)
            #pragma unroll
            for (int r = 0; r < 4; ++r)
                lx[q * 4 + r][ct * 16 + c] = fmaxf(acc[ct][r] * s1[ct] + o1[ct], 0.f);
        {
            const float* pr = &lx[c][0];
            float tb[8];
            *(float4*)tb       = *(const float4*)(pr + q * 8);
            *(float4*)(tb + 4) = *(const float4*)(pr + q * 8 + 4);
            a0 = packbf8(tb);
            *(float4*)tb       = *(const float4*)(pr + 32 + q * 8);
            *(float4*)(tb + 4) = *(const float4*)(pr + 32 + q * 8 + 4);
            a1 = packbf8(tb);
        }

        // ---- Wm2 -> BN -> ReLU -> dot Wm3 -> sigmoid ----
        #pragma unroll
        for (int ct = 0; ct < 4; ++ct) {
            f32x4 a = {0.f, 0.f, 0.f, 0.f};
            a = MFMA(a0, B2[0][ct], a);
            a = MFMA(a1, B2[1][ct], a);
            acc[ct] = a;
        }
        float tr[4];
        #pragma unroll
        for (int r = 0; r < 4; ++r) {
            float hs = 0.f;
            #pragma unroll
            for (int ct = 0; ct < 4; ++ct) {
                float h2 = fmaxf(acc[ct][r] * s2[ct] + o2[ct], 0.f);
                hs = fmaf(h2, w3[ct], hs);
            }
            tr[r] = hs;
        }
        #pragma unroll
        for (int m = 1; m < 16; m <<= 1)
            #pragma unroll
            for (int r = 0; r < 4; ++r) tr[r] += __shfl_xor(tr[r], m, 16);
        if (c == 0) {
            #pragma unroll
            for (int r = 0; r < 4; ++r) {
                int row = t * 16 + q * 4 + r;
                if (row < N)
                    out[(size_t)N * 64 + row] = 1.f / (1.f + expf(-(tr[r] + b3)));
            }
        }
    }
}

extern "C" void kernel_launch(void* const* d_in, const int* in_sizes, int n_in,
                              void* d_out, int out_size, void* d_ws, size_t ws_size,
                              hipStream_t stream) {
    const float* x   = (const float*)d_in[0];
    const int*   ei  = (const int*)  d_in[1];
    const float* Wp1 = (const float*)d_in[2];
    const float* bp1 = (const float*)d_in[3];
    const float* Wn1 = (const float*)d_in[4];
    const float* bn1 = (const float*)d_in[5];
    const float* Wp2 = (const float*)d_in[6];
    const float* bp2 = (const float*)d_in[7];
    const float* Wn2 = (const float*)d_in[8];
    const float* bn2 = (const float*)d_in[9];
    const float* Ww  = (const float*)d_in[10];
    const float* bw  = (const float*)d_in[11];
    const float* Wm1 = (const float*)d_in[12];
    const float* bm1 = (const float*)d_in[13];
    const float* g1  = (const float*)d_in[14];
    const float* be1 = (const float*)d_in[15];
    const float* rm1 = (const float*)d_in[16];
    const float* rv1 = (const float*)d_in[17];
    const float* Wm2 = (const float*)d_in[18];
    const float* bm2 = (const float*)d_in[19];
    const float* g2  = (const float*)d_in[20];
    const float* be2 = (const float*)d_in[21];
    const float* rm2 = (const float*)d_in[22];
    const float* rv2 = (const float*)d_in[23];
    const float* Wm3 = (const float*)d_in[24];
    const float* bm3 = (const float*)d_in[25];
    float* out = (float*)d_out;

    int N = in_sizes[0] / 64;
    int E = in_sizes[1] / 3;

    // ws layout (52.0 MB for N=100K): plist | nlist | pcur | ncur | agg(bf16 N x 128)
    int* plist = (int*)d_ws;
    int* nlist = plist + (size_t)N * CAP;
    int* pcur  = nlist + (size_t)N * CAP;
    int* ncur  = pcur + N;
    __hip_bfloat16* agg = (__hip_bfloat16*)(ncur + N);   // also hosts z2b (stride 128)

    // d_out z region staging: z1b = first half, xb = second half (dead by mlp).
    __hip_bfloat16* z1b = (__hip_bfloat16*)out;                              // N x 64
    __hip_bfloat16* xb  = (__hip_bfloat16*)((char*)d_out + (size_t)N * 128); // N x 64

    hipMemsetAsync(pcur, 0, 2 * (size_t)N * sizeof(int), stream);

    int buildBlocks = (E + 1023) / 1024;
    int castBlocks  = (N * 64 / 4 + 255) / 256;
    pg_build_cast<<<buildBlocks + castBlocks, 256, 0, stream>>>(
        ei, plist, nlist, pcur, ncur, E, buildBlocks, x, xb, N * 64);

    int nb = (N + 63) / 64;
    const int gb = 512, nwv = gb * 4;
    pg_gather<<<nb, 256, 0, stream>>>(xb, plist, nlist, pcur, ncur, agg, N);
    pg_gemm1<<<gb, 256, 0, stream>>>(xb, agg, Wp1, bp1, Wn1, bn1, z1b, N, nwv);
    pg_gather<<<nb, 256, 0, stream>>>(z1b, plist, nlist, pcur, ncur, agg, N);
    pg_gemm2<<<gb, 256, 0, stream>>>(z1b, agg, Wp2, bp2, Wn2, bn2, N, nwv);
    pg_mlp<<<gb, 256, 0, stream>>>(out, agg, Ww, bw,
                                   Wm1, bm1, g1, be1, rm1, rv1,
                                   Wm2, bm2, g2, be2, rm2, rv2,
                                   Wm3, bm3, N, nwv);
}

// Round 12
// 246.913 us; speedup vs baseline: 1.0838x; 1.0266x over previous
//
#include <hip/hip_runtime.h>
#include <hip/hip_bf16.h>

#define CAP 32   // padded adjacency slots per node per sign (Poisson λ≈6.25)

typedef __attribute__((ext_vector_type(8))) short bf16x8;
typedef __attribute__((ext_vector_type(4))) float f32x4;

#define MFMA(a, b, c) __builtin_amdgcn_mfma_f32_16x16x32_bf16(a, b, c, 0, 0, 0)

__device__ __forceinline__ unsigned short bf16rn(float f) {
    unsigned u = __builtin_bit_cast(unsigned, f);
    u += 0x7fffu + ((u >> 16) & 1u);
    return (unsigned short)(u >> 16);
}
__device__ __forceinline__ float bf16lo(unsigned u) {
    return __builtin_bit_cast(float, u << 16);
}
__device__ __forceinline__ float bf16hi(unsigned u) {
    return __builtin_bit_cast(float, u & 0xffff0000u);
}
__device__ __forceinline__ unsigned pack2(float a, float b) {
    return (unsigned)bf16rn(a) | ((unsigned)bf16rn(b) << 16);
}
__device__ __forceinline__ bf16x8 packbf8(const float* p) {
    bf16x8 r;
    #pragma unroll
    for (int j = 0; j < 8; ++j) r[j] = (short)bf16rn(p[j]);
    return r;
}

// B-frag from row-major f32 W[K][NN]: elem j = W[kt*32 + q*8 + j][ct*16 + c]
__device__ __forceinline__ bf16x8 wfrag(const float* __restrict__ W, int NN,
                                        int kt, int ct, int q, int c) {
    const float* base = W + (kt * 32 + q * 8) * NN + ct * 16 + c;
    float t[8];
    #pragma unroll
    for (int j = 0; j < 8; ++j) t[j] = base[j * NN];
    return packbf8(t);
}

// A-frag: row-major bf16 source, contiguous 32-col window starting at cw
__device__ __forceinline__ bf16x8 afrag_bf16(const __hip_bfloat16* row, int cw, int q) {
    return *(const bf16x8*)((const short*)row + cw + q * 8);
}

// ---------------------------------------------------------------------------
// Fused: adjacency build (4 edges/thread) + x->bf16 cast.
// ---------------------------------------------------------------------------
__global__ __launch_bounds__(256) void pg_build_cast(
    const int* __restrict__ ei,
    int* __restrict__ plist, int* __restrict__ nlist,
    int* __restrict__ pcur, int* __restrict__ ncur, int E, int buildBlocks,
    const float* __restrict__ x, __hip_bfloat16* __restrict__ xb, int nx)
{
    int b = blockIdx.x;
    if (b >= buildBlocks) {
        int i = ((b - buildBlocks) * 256 + threadIdx.x) * 4;
        if (i < nx) {
            float4 v = *(const float4*)(x + i);
            ushort4 o;
            o.x = bf16rn(v.x); o.y = bf16rn(v.y);
            o.z = bf16rn(v.z); o.w = bf16rn(v.w);
            *(ushort4*)((unsigned short*)xb + i) = o;
        }
        return;
    }
    int e0 = (b * 256 + threadIdx.x) * 4;
    int s[4], d[4], sg[4];
    bool ok[4];
    #pragma unroll
    for (int k = 0; k < 4; ++k) {
        int e = e0 + k;
        ok[k] = (e < E);
        int ee = ok[k] ? e : 0;
        s[k]  = ei[3 * ee + 0];
        d[k]  = ei[3 * ee + 1];
        sg[k] = ei[3 * ee + 2];
    }
    int slot[4];
    int* dstl[4];
    #pragma unroll
    for (int k = 0; k < 4; ++k) {
        int* cur = (sg[k] > 0) ? pcur : ncur;
        dstl[k]  = ((sg[k] > 0) ? plist : nlist) + (size_t)d[k] * CAP;
        slot[k]  = ok[k] ? atomicAdd(cur + d[k], 1) : CAP;
    }
    #pragma unroll
    for (int k = 0; k < 4; ++k)
        if (slot[k] < CAP) dstl[k][slot[k]] = s[k];
}

// ---------------------------------------------------------------------------
// Gather: per node, pos/neg mean of bf16 src rows -> packed bf16 agg row
//   agg[i] = [ pmean(64) | nmean(64) ]
// Tail-free scheduling: grid = machine-filling; each WAVE grid-strides over
// 4-node groups (quantum = 1 group). Body: 4 slots per VMEM instruction
// (grp=lane>>4, dwordx2 each), EXEC-MASKED (no dummy transactions).
// ---------------------------------------------------------------------------
__global__ __launch_bounds__(256, 6) void pg_gather(
    const __hip_bfloat16* __restrict__ src,
    const int* __restrict__ plist, const int* __restrict__ nlist,
    const int* __restrict__ pcur, const int* __restrict__ ncur,
    __hip_bfloat16* __restrict__ agg, int N)
{
    int tid = threadIdx.x;
    int w = tid >> 6, lane = tid & 63;
    int grp = lane >> 4;      // slot offset within the 4-slot batch
    int q   = lane & 15;      // col-quad: cols 4q..4q+3

    int gwave  = blockIdx.x * 4 + w;
    int nwaves = gridDim.x * 4;
    int ngroups = (N + 3) >> 2;

    #pragma unroll 1
    for (int g = gwave; g < ngroups; g += nwaves) {
        int i0 = g * 4;
        int pd[4], nd[4], pde[4], nde[4], pl[4], nl[4];
        #pragma unroll
        for (int n = 0; n < 4; ++n) {
            int i = min(i0 + n, N - 1);
            pd[n] = __builtin_amdgcn_readfirstlane(pcur[i]);
            nd[n] = __builtin_amdgcn_readfirstlane(ncur[i]);
            pde[n] = min(pd[n], CAP);
            nde[n] = min(nd[n], CAP);
            pl[n] = plist[(size_t)i * CAP + (lane & 31)];
            nl[n] = nlist[(size_t)i * CAP + (lane & 31)];
        }
        int maxd = 0;
        #pragma unroll
        for (int n = 0; n < 4; ++n) maxd = max(maxd, max(pde[n], nde[n]));

        float ps[4][4], ns[4][4];
        #pragma unroll
        for (int n = 0; n < 4; ++n)
            #pragma unroll
            for (int r = 0; r < 4; ++r) { ps[n][r] = 0.f; ns[n][r] = 0.f; }

        #pragma unroll 1
        for (int e = 0; e < maxd; e += 4) {
            #pragma unroll
            for (int n = 0; n < 4; ++n) {
                int p0 = __builtin_amdgcn_readlane(pl[n], (e + 0) < pde[n] ? e + 0 : 0);
                int p1 = __builtin_amdgcn_readlane(pl[n], (e + 1) < pde[n] ? e + 1 : 0);
                int p2 = __builtin_amdgcn_readlane(pl[n], (e + 2) < pde[n] ? e + 2 : 0);
                int p3 = __builtin_amdgcn_readlane(pl[n], (e + 3) < pde[n] ? e + 3 : 0);
                int m0 = __builtin_amdgcn_readlane(nl[n], (e + 0) < nde[n] ? e + 0 : 0);
                int m1 = __builtin_amdgcn_readlane(nl[n], (e + 1) < nde[n] ? e + 1 : 0);
                int m2 = __builtin_amdgcn_readlane(nl[n], (e + 2) < nde[n] ? e + 2 : 0);
                int m3 = __builtin_amdgcn_readlane(nl[n], (e + 3) < nde[n] ? e + 3 : 0);
                unsigned sp = (unsigned)(grp == 0 ? p0 : grp == 1 ? p1 : grp == 2 ? p2 : p3);
                unsigned sn = (unsigned)(grp == 0 ? m0 : grp == 1 ? m1 : grp == 2 ? m2 : m3);
                if (e + grp < pde[n]) {        // exec-masked: no dummy txns
                    sp = sp < (unsigned)N ? sp : 0u;
                    uint2 pv = *((const uint2*)(src + ((size_t)sp << 6)) + q);
                    ps[n][0] += bf16lo(pv.x); ps[n][1] += bf16hi(pv.x);
                    ps[n][2] += bf16lo(pv.y); ps[n][3] += bf16hi(pv.y);
                }
                if (e + grp < nde[n]) {
                    sn = sn < (unsigned)N ? sn : 0u;
                    uint2 nv = *((const uint2*)(src + ((size_t)sn << 6)) + q);
                    ns[n][0] += bf16lo(nv.x); ns[n][1] += bf16hi(nv.x);
                    ns[n][2] += bf16lo(nv.y); ns[n][3] += bf16hi(nv.y);
                }
            }
        }
        #pragma unroll
        for (int n = 0; n < 4; ++n) {
            #pragma unroll
            for (int r = 0; r < 4; ++r) {
                ps[n][r] += __shfl_xor(ps[n][r], 16);
                ps[n][r] += __shfl_xor(ps[n][r], 32);
                ns[n][r] += __shfl_xor(ns[n][r], 16);
                ns[n][r] += __shfl_xor(ns[n][r], 32);
            }
            int i = i0 + n;
            if (i < N) {
                float invp = 1.f / fmaxf((float)pd[n], 1.f);
                float invn = 1.f / fmaxf((float)nd[n], 1.f);
                uint2* arow = (uint2*)(agg + ((size_t)i << 7));
                if (grp == 0) {
                    uint2 ow;
                    ow.x = pack2(ps[n][0] * invp, ps[n][1] * invp);
                    ow.y = pack2(ps[n][2] * invp, ps[n][3] * invp);
                    arow[q] = ow;
                } else if (grp == 1) {
                    uint2 ow;
                    ow.x = pack2(ns[n][0] * invn, ns[n][1] * invn);
                    ow.y = pack2(ns[n][2] * invn, ns[n][3] * invn);
                    arow[16 + q] = ow;
                }
            }
        }
    }
}

// ---------------------------------------------------------------------------
// GEMM1 (MFMA): z1b = tanh([ap,x]@Wp1 | [an,x]@Wn1), bf16 in / bf16 out.
// ---------------------------------------------------------------------------
__global__ __launch_bounds__(256, 3) void pg_gemm1(
    const __hip_bfloat16* __restrict__ xb, const __hip_bfloat16* __restrict__ agg,
    const float* __restrict__ Wp, const float* __restrict__ bp,
    const float* __restrict__ Wn, const float* __restrict__ bn,
    __hip_bfloat16* __restrict__ z1b, int N, int nwv)
{
    int tid = threadIdx.x;
    int w = tid >> 6, lane = tid & 63;
    int q = lane >> 4, c = lane & 15;

    bf16x8 B[2][4][2];
    #pragma unroll
    for (int kt = 0; kt < 4; ++kt)
        #pragma unroll
        for (int ct = 0; ct < 2; ++ct) {
            B[0][kt][ct] = wfrag(Wp, 32, kt, ct, q, c);
            B[1][kt][ct] = wfrag(Wn, 32, kt, ct, q, c);
        }
    float bias[2][2];
    #pragma unroll
    for (int ct = 0; ct < 2; ++ct) {
        bias[0][ct] = bp[ct * 16 + c];
        bias[1][ct] = bn[ct * 16 + c];
    }

    int ntiles = (N + 15) >> 4;
    #pragma unroll 1
    for (int t = blockIdx.x * 4 + w; t < ntiles; t += nwv) {
        int i = min(t * 16 + c, N - 1);
        const __hip_bfloat16* arow = agg + ((size_t)i << 7);
        const __hip_bfloat16* xrow = xb + ((size_t)i << 6);
        bf16x8 aA0 = afrag_bf16(arow, 0, q);
        bf16x8 aA1 = afrag_bf16(arow, 32, q);
        bf16x8 aA2 = afrag_bf16(arow, 64, q);
        bf16x8 aA3 = afrag_bf16(arow, 96, q);
        bf16x8 aX0 = afrag_bf16(xrow, 0, q);
        bf16x8 aX1 = afrag_bf16(xrow, 32, q);
        f32x4 acc[2][2];
        #pragma unroll
        for (int ct = 0; ct < 2; ++ct) {
            f32x4 a = {0.f, 0.f, 0.f, 0.f};
            a = MFMA(aA0, B[0][0][ct], a);
            a = MFMA(aA1, B[0][1][ct], a);
            a = MFMA(aX0, B[0][2][ct], a);
            a = MFMA(aX1, B[0][3][ct], a);
            acc[0][ct] = a;
            f32x4 b = {0.f, 0.f, 0.f, 0.f};
            b = MFMA(aA2, B[1][0][ct], b);
            b = MFMA(aA3, B[1][1][ct], b);
            b = MFMA(aX0, B[1][2][ct], b);
            b = MFMA(aX1, B[1][3][ct], b);
            acc[1][ct] = b;
        }
        #pragma unroll
        for (int h = 0; h < 2; ++h)
            #pragma unroll
            for (int ct = 0; ct < 2; ++ct)
                #pragma unroll
                for (int r = 0; r < 4; ++r) {
                    int row = t * 16 + q * 4 + r;
                    if (row < N)
                        z1b[(size_t)row * 64 + h * 32 + ct * 16 + c] =
                            __float2bfloat16(tanhf(acc[h][ct][r] + bias[h][ct]));
                }
    }
}

// ---------------------------------------------------------------------------
// GEMM2 (MFMA): z2 = tanh([agg-windows, z1]@Wp2 | ...@Wn2).
// z2b written bf16 into agg region cols 0..63 (stride 128) -> row-local, safe.
// ---------------------------------------------------------------------------
__global__ __launch_bounds__(256, 3) void pg_gemm2(
    const __hip_bfloat16* __restrict__ z1b, __hip_bfloat16* agg,
    const float* __restrict__ Wp2, const float* __restrict__ bp2,
    const float* __restrict__ Wn2, const float* __restrict__ bn2,
    int N, int nwv)
{
    int tid = threadIdx.x;
    int w = tid >> 6, lane = tid & 63;
    int q = lane >> 4, c = lane & 15;

    bf16x8 B[2][3][2];
    #pragma unroll
    for (int kt = 0; kt < 3; ++kt)
        #pragma unroll
        for (int ct = 0; ct < 2; ++ct) {
            B[0][kt][ct] = wfrag(Wp2, 32, kt, ct, q, c);
            B[1][kt][ct] = wfrag(Wn2, 32, kt, ct, q, c);
        }
    float bias[2][2];
    #pragma unroll
    for (int ct = 0; ct < 2; ++ct) {
        bias[0][ct] = bp2[ct * 16 + c];
        bias[1][ct] = bn2[ct * 16 + c];
    }

    int ntiles = (N + 15) >> 4;
    #pragma unroll 1
    for (int t = blockIdx.x * 4 + w; t < ntiles; t += nwv) {
        int i = min(t * 16 + c, N - 1);
        const __hip_bfloat16* arow = agg + ((size_t)i << 7);
        const __hip_bfloat16* zrow = z1b + ((size_t)i << 6);
        bf16x8 ap0 = afrag_bf16(arow, 0, q);
        bf16x8 ap1 = afrag_bf16(arow, 96, q);
        bf16x8 an0 = afrag_bf16(arow, 32, q);
        bf16x8 an1 = afrag_bf16(arow, 64, q);
        bf16x8 az0 = afrag_bf16(zrow, 0, q);
        bf16x8 az1 = afrag_bf16(zrow, 32, q);
        f32x4 acc[2][2];
        #pragma unroll
        for (int ct = 0; ct < 2; ++ct) {
            f32x4 a = {0.f, 0.f, 0.f, 0.f};
            a = MFMA(ap0, B[0][0][ct], a);
            a = MFMA(ap1, B[0][1][ct], a);
            a = MFMA(az0, B[0][2][ct], a);
            acc[0][ct] = a;
            f32x4 b = {0.f, 0.f, 0.f, 0.f};
            b = MFMA(an0, B[1][0][ct], b);
            b = MFMA(an1, B[1][1][ct], b);
            b = MFMA(az1, B[1][2][ct], b);
            acc[1][ct] = b;
        }
        #pragma unroll
        for (int h = 0; h < 2; ++h)
            #pragma unroll
            for (int ct = 0; ct < 2; ++ct)
                #pragma unroll
                for (int r = 0; r < 4; ++r) {
                    int row = t * 16 + q * 4 + r;
                    if (row < N)
                        agg[(size_t)row * 128 + h * 32 + ct * 16 + c] =
                            __float2bfloat16(tanhf(acc[h][ct][r] + bias[h][ct]));
                }
    }
}

// ---------------------------------------------------------------------------
// MLP head (MFMA chain): z = tanh(z2@Ww+bw) -> out; BN/ReLU x2; dot Wm3 ->
// sigmoid prob. z2b read bf16 (stride 128). LDS transpose between stages.
// ---------------------------------------------------------------------------
__global__ __launch_bounds__(256, 2) void pg_mlp(
    float* out, const __hip_bfloat16* __restrict__ z2b,
    const float* __restrict__ Ww,  const float* __restrict__ bw,
    const float* __restrict__ Wm1, const float* __restrict__ bm1,
    const float* __restrict__ g1,  const float* __restrict__ be1,
    const float* __restrict__ rm1, const float* __restrict__ rv1,
    const float* __restrict__ Wm2, const float* __restrict__ bm2,
    const float* __restrict__ g2,  const float* __restrict__ be2,
    const float* __restrict__ rm2, const float* __restrict__ rv2,
    const float* __restrict__ Wm3, const float* __restrict__ bm3,
    int N, int nwv)
{
    __shared__ float xpos[4][16][68];
    int tid = threadIdx.x;
    int w = tid >> 6, lane = tid & 63;
    int q = lane >> 4, c = lane & 15;
    float (*lx)[68] = xpos[w];

    bf16x8 Bw[2][4], B1[2][4], B2[2][4];
    #pragma unroll
    for (int kt = 0; kt < 2; ++kt)
        #pragma unroll
        for (int ct = 0; ct < 4; ++ct) {
            Bw[kt][ct] = wfrag(Ww,  64, kt, ct, q, c);
            B1[kt][ct] = wfrag(Wm1, 64, kt, ct, q, c);
            B2[kt][ct] = wfrag(Wm2, 64, kt, ct, q, c);
        }
    float bwv[4], s1[4], o1[4], s2[4], o2[4], w3[4];
    #pragma unroll
    for (int ct = 0; ct < 4; ++ct) {
        int cc = ct * 16 + c;
        bwv[ct] = bw[cc];
        float a = g1[cc] * rsqrtf(rv1[cc] + 1e-5f);
        s1[ct] = a; o1[ct] = (bm1[cc] - rm1[cc]) * a + be1[cc];
        float b = g2[cc] * rsqrtf(rv2[cc] + 1e-5f);
        s2[ct] = b; o2[ct] = (bm2[cc] - rm2[cc]) * b + be2[cc];
        w3[ct] = Wm3[cc];
    }
    float b3 = bm3[0];

    int ntiles = (N + 15) >> 4;
    #pragma unroll 1
    for (int t = blockIdx.x * 4 + w; t < ntiles; t += nwv) {
        int i = min(t * 16 + c, N - 1);
        const __hip_bfloat16* zrow = z2b + ((size_t)i << 7);
        bf16x8 a0 = afrag_bf16(zrow, 0, q);
        bf16x8 a1 = afrag_bf16(zrow, 32, q);
        f32x4 acc[4];

        // ---- Ww -> tanh -> final z (global + LDS) ----
        #pragma unroll
        for (int ct = 0; ct < 4; ++ct) {
            f32x4 a = {0.f, 0.f, 0.f, 0.f};
            a = MFMA(a0, Bw[0][ct], a);
            a = MFMA(a1, Bw[1][ct], a);
            acc[ct] = a;
        }
        #pragma unroll
        for (int ct = 0; ct < 4; ++ct)
            #pragma unroll
            for (int r = 0; r < 4; ++r) {
                int row = t * 16 + q * 4 + r;
                float v = tanhf(acc[ct][r] + bwv[ct]);
                if (row < N) out[(size_t)row * 64 + ct * 16 + c] = v;
                lx[q * 4 + r][ct * 16 + c] = v;
            }
        {
            const float* pr = &lx[c][0];
            float tb[8];
            *(float4*)tb       = *(const float4*)(pr + q * 8);
            *(float4*)(tb + 4) = *(const float4*)(pr + q * 8 + 4);
            a0 = packbf8(tb);
            *(float4*)tb       = *(const float4*)(pr + 32 + q * 8);
            *(float4*)(tb + 4) = *(const float4*)(pr + 32 + q * 8 + 4);
            a1 = packbf8(tb);
        }

        // ---- Wm1 -> BN -> ReLU ----
        #pragma unroll
        for (int ct = 0; ct < 4; ++ct) {
            f32x4 a = {0.f, 0.f, 0.f, 0.f};
            a = MFMA(a0, B1[0][ct], a);
            a = MFMA(a1, B1[1][ct], a);
            acc[ct] = a;
        }
        #pragma unroll
        for (int ct = 0; ct < 4; ++ct)
            #pragma unroll
            for (int r = 0; r < 4; ++r)
                lx[q * 4 + r][ct * 16 + c] = fmaxf(acc[ct][r] * s1[ct] + o1[ct], 0.f);
        {
            const float* pr = &lx[c][0];
            float tb[8];
            *(float4*)tb       = *(const float4*)(pr + q * 8);
            *(float4*)(tb + 4) = *(const float4*)(pr + q * 8 + 4);
            a0 = packbf8(tb);
            *(float4*)tb       = *(const float4*)(pr + 32 + q * 8);
            *(float4*)(tb + 4) = *(const float4*)(pr + 32 + q * 8 + 4);
            a1 = packbf8(tb);
        }

        // ---- Wm2 -> BN -> ReLU -> dot Wm3 -> sigmoid ----
        #pragma unroll
        for (int ct = 0; ct < 4; ++ct) {
            f32x4 a = {0.f, 0.f, 0.f, 0.f};
            a = MFMA(a0, B2[0][ct], a);
            a = MFMA(a1, B2[1][ct], a);
            acc[ct] = a;
        }
        float tr[4];
        #pragma unroll
        for (int r = 0; r < 4; ++r) {
            float hs = 0.f;
            #pragma unroll
            for (int ct = 0; ct < 4; ++ct) {
                float h2 = fmaxf(acc[ct][r] * s2[ct] + o2[ct], 0.f);
                hs = fmaf(h2, w3[ct], hs);
            }
            tr[r] = hs;
        }
        #pragma unroll
        for (int m = 1; m < 16; m <<= 1)
            #pragma unroll
            for (int r = 0; r < 4; ++r) tr[r] += __shfl_xor(tr[r], m, 16);
        if (c == 0) {
            #pragma unroll
            for (int r = 0; r < 4; ++r) {
                int row = t * 16 + q * 4 + r;
                if (row < N)
                    out[(size_t)N * 64 + row] = 1.f / (1.f + expf(-(tr[r] + b3)));
            }
        }
    }
}

extern "C" void kernel_launch(void* const* d_in, const int* in_sizes, int n_in,
                              void* d_out, int out_size, void* d_ws, size_t ws_size,
                              hipStream_t stream) {
    const float* x   = (const float*)d_in[0];
    const int*   ei  = (const int*)  d_in[1];
    const float* Wp1 = (const float*)d_in[2];
    const float* bp1 = (const float*)d_in[3];
    const float* Wn1 = (const float*)d_in[4];
    const float* bn1 = (const float*)d_in[5];
    const float* Wp2 = (const float*)d_in[6];
    const float* bp2 = (const float*)d_in[7];
    const float* Wn2 = (const float*)d_in[8];
    const float* bn2 = (const float*)d_in[9];
    const float* Ww  = (const float*)d_in[10];
    const float* bw  = (const float*)d_in[11];
    const float* Wm1 = (const float*)d_in[12];
    const float* bm1 = (const float*)d_in[13];
    const float* g1  = (const float*)d_in[14];
    const float* be1 = (const float*)d_in[15];
    const float* rm1 = (const float*)d_in[16];
    const float* rv1 = (const float*)d_in[17];
    const float* Wm2 = (const float*)d_in[18];
    const float* bm2 = (const float*)d_in[19];
    const float* g2  = (const float*)d_in[20];
    const float* be2 = (const float*)d_in[21];
    const float* rm2 = (const float*)d_in[22];
    const float* rv2 = (const float*)d_in[23];
    const float* Wm3 = (const float*)d_in[24];
    const float* bm3 = (const float*)d_in[25];
    float* out = (float*)d_out;

    int N = in_sizes[0] / 64;
    int E = in_sizes[1] / 3;

    // ws layout (52.0 MB for N=100K): plist | nlist | pcur | ncur | agg(bf16 N x 128)
    int* plist = (int*)d_ws;
    int* nlist = plist + (size_t)N * CAP;
    int* pcur  = nlist + (size_t)N * CAP;
    int* ncur  = pcur + N;
    __hip_bfloat16* agg = (__hip_bfloat16*)(ncur + N);   // also hosts z2b (stride 128)

    // d_out z region staging: z1b = first half, xb = second half (dead by mlp).
    __hip_bfloat16* z1b = (__hip_bfloat16*)out;                              // N x 64
    __hip_bfloat16* xb  = (__hip_bfloat16*)((char*)d_out + (size_t)N * 128); // N x 64

    hipMemsetAsync(pcur, 0, 2 * (size_t)N * sizeof(int), stream);

    int buildBlocks = (E + 1023) / 1024;
    int castBlocks  = (N * 64 / 4 + 255) / 256;
    pg_build_cast<<<buildBlocks + castBlocks, 256, 0, stream>>>(
        ei, plist, nlist, pcur, ncur, E, buildBlocks, x, xb, N * 64);

    // Tail-free gather grid: exactly machine-filling at 6 blocks/CU.
    const int gatherBlocks = 1536;
    const int gb = 512, nwv = gb * 4;
    pg_gather<<<gatherBlocks, 256, 0, stream>>>(xb, plist, nlist, pcur, ncur, agg, N);
    pg_gemm1<<<gb, 256, 0, stream>>>(xb, agg, Wp1, bp1, Wn1, bn1, z1b, N, nwv);
    pg_gather<<<gatherBlocks, 256, 0, stream>>>(z1b, plist, nlist, pcur, ncur, agg, N);
    pg_gemm2<<<gb, 256, 0, stream>>>(z1b, agg, Wp2, bp2, Wn2, bn2, N, nwv);
    pg_mlp<<<gb, 256, 0, stream>>>(out, agg, Ww, bw,
                                   Wm1, bm1, g1, be1, rm1, rv1,
                                   Wm2, bm2, g2, be2, rm2, rv2,
                                   Wm3, bm3, N, nwv);
}

// Round 13
// 233.460 us; speedup vs baseline: 1.1463x; 1.0576x over previous
//
#include <hip/hip_runtime.h>
#include <hip/hip_bf16.h>

// Adjacency record: 32 ints, line-aligned. rec[0]=count, rec[1+slot]=src.
// Effective capacity 31 slots (Poisson λ≈6.25 -> overflow P ~ 1e-14).
#define RSTRIDE 32
#define RCAP    31

typedef __attribute__((ext_vector_type(8))) short bf16x8;
typedef __attribute__((ext_vector_type(4))) float f32x4;

#define MFMA(a, b, c) __builtin_amdgcn_mfma_f32_16x16x32_bf16(a, b, c, 0, 0, 0)

__device__ __forceinline__ unsigned short bf16rn(float f) {
    unsigned u = __builtin_bit_cast(unsigned, f);
    u += 0x7fffu + ((u >> 16) & 1u);
    return (unsigned short)(u >> 16);
}
__device__ __forceinline__ float bf16lo(unsigned u) {
    return __builtin_bit_cast(float, u << 16);
}
__device__ __forceinline__ float bf16hi(unsigned u) {
    return __builtin_bit_cast(float, u & 0xffff0000u);
}
__device__ __forceinline__ unsigned pack2(float a, float b) {
    return (unsigned)bf16rn(a) | ((unsigned)bf16rn(b) << 16);
}
__device__ __forceinline__ bf16x8 packbf8(const float* p) {
    bf16x8 r;
    #pragma unroll
    for (int j = 0; j < 8; ++j) r[j] = (short)bf16rn(p[j]);
    return r;
}

// B-frag from row-major f32 W[K][NN]: elem j = W[kt*32 + q*8 + j][ct*16 + c]
__device__ __forceinline__ bf16x8 wfrag(const float* __restrict__ W, int NN,
                                        int kt, int ct, int q, int c) {
    const float* base = W + (kt * 32 + q * 8) * NN + ct * 16 + c;
    float t[8];
    #pragma unroll
    for (int j = 0; j < 8; ++j) t[j] = base[j * NN];
    return packbf8(t);
}

// A-frag: row-major bf16 source, contiguous 32-col window starting at cw
__device__ __forceinline__ bf16x8 afrag_bf16(const __hip_bfloat16* row, int cw, int q) {
    return *(const bf16x8*)((const short*)row + cw + q * 8);
}

// ---------------------------------------------------------------------------
// Fused: adjacency build (4 edges/thread, counter+slots co-located in one
// line-aligned record -> ~1 line-touch per edge) + x->bf16 cast.
// ---------------------------------------------------------------------------
__global__ __launch_bounds__(256) void pg_build_cast(
    const int* __restrict__ ei,
    int* __restrict__ prec, int* __restrict__ nrec, int E, int buildBlocks,
    const float* __restrict__ x, __hip_bfloat16* __restrict__ xb, int nx)
{
    int b = blockIdx.x;
    if (b >= buildBlocks) {
        int i = ((b - buildBlocks) * 256 + threadIdx.x) * 4;
        if (i < nx) {
            float4 v = *(const float4*)(x + i);
            ushort4 o;
            o.x = bf16rn(v.x); o.y = bf16rn(v.y);
            o.z = bf16rn(v.z); o.w = bf16rn(v.w);
            *(ushort4*)((unsigned short*)xb + i) = o;
        }
        return;
    }
    int e0 = (b * 256 + threadIdx.x) * 4;
    int s[4], d[4], sg[4];
    bool ok[4];
    #pragma unroll
    for (int k = 0; k < 4; ++k) {
        int e = e0 + k;
        ok[k] = (e < E);
        int ee = ok[k] ? e : 0;
        s[k]  = ei[3 * ee + 0];
        d[k]  = ei[3 * ee + 1];
        sg[k] = ei[3 * ee + 2];
    }
    int* rec[4];
    int slot[4];
    #pragma unroll
    for (int k = 0; k < 4; ++k) {
        rec[k]  = ((sg[k] > 0) ? prec : nrec) + (size_t)d[k] * RSTRIDE;
        slot[k] = ok[k] ? atomicAdd(rec[k], 1) : RCAP;
    }
    #pragma unroll
    for (int k = 0; k < 4; ++k)
        if (slot[k] < RCAP) rec[k][1 + slot[k]] = s[k];
}

// ---------------------------------------------------------------------------
// Gather: per node, pos/neg mean of bf16 src rows -> packed bf16 agg row
//   agg[i] = [ pmean(64) | nmean(64) ]
// Tail-free wave grid-stride over 4-node groups; 4 slots per VMEM instr
// (grp=lane>>4, dwordx2 each), EXEC-MASKED (no dummy transactions).
// ---------------------------------------------------------------------------
__global__ __launch_bounds__(256, 6) void pg_gather(
    const __hip_bfloat16* __restrict__ src,
    const int* __restrict__ prec, const int* __restrict__ nrec,
    __hip_bfloat16* __restrict__ agg, int N)
{
    int tid = threadIdx.x;
    int w = tid >> 6, lane = tid & 63;
    int grp = lane >> 4;      // slot offset within the 4-slot batch
    int q   = lane & 15;      // col-quad: cols 4q..4q+3

    int gwave  = blockIdx.x * 4 + w;
    int nwaves = gridDim.x * 4;
    int ngroups = (N + 3) >> 2;

    #pragma unroll 1
    for (int g = gwave; g < ngroups; g += nwaves) {
        int i0 = g * 4;
        int pd[4], nd[4], pde[4], nde[4], pl[4], nl[4];
        #pragma unroll
        for (int n = 0; n < 4; ++n) {
            int i = min(i0 + n, N - 1);
            const int* pr = prec + (size_t)i * RSTRIDE;
            const int* nr = nrec + (size_t)i * RSTRIDE;
            pd[n] = __builtin_amdgcn_readfirstlane(pr[0]);
            nd[n] = __builtin_amdgcn_readfirstlane(nr[0]);
            pde[n] = min(pd[n], RCAP);
            nde[n] = min(nd[n], RCAP);
            pl[n] = pr[1 + (lane & 31)];   // lane 31 probes next record; never selected
            nl[n] = nr[1 + (lane & 31)];
        }
        int maxd = 0;
        #pragma unroll
        for (int n = 0; n < 4; ++n) maxd = max(maxd, max(pde[n], nde[n]));

        float ps[4][4], ns[4][4];
        #pragma unroll
        for (int n = 0; n < 4; ++n)
            #pragma unroll
            for (int r = 0; r < 4; ++r) { ps[n][r] = 0.f; ns[n][r] = 0.f; }

        #pragma unroll 1
        for (int e = 0; e < maxd; e += 4) {
            #pragma unroll
            for (int n = 0; n < 4; ++n) {
                int p0 = __builtin_amdgcn_readlane(pl[n], (e + 0) < pde[n] ? e + 0 : 0);
                int p1 = __builtin_amdgcn_readlane(pl[n], (e + 1) < pde[n] ? e + 1 : 0);
                int p2 = __builtin_amdgcn_readlane(pl[n], (e + 2) < pde[n] ? e + 2 : 0);
                int p3 = __builtin_amdgcn_readlane(pl[n], (e + 3) < pde[n] ? e + 3 : 0);
                int m0 = __builtin_amdgcn_readlane(nl[n], (e + 0) < nde[n] ? e + 0 : 0);
                int m1 = __builtin_amdgcn_readlane(nl[n], (e + 1) < nde[n] ? e + 1 : 0);
                int m2 = __builtin_amdgcn_readlane(nl[n], (e + 2) < nde[n] ? e + 2 : 0);
                int m3 = __builtin_amdgcn_readlane(nl[n], (e + 3) < nde[n] ? e + 3 : 0);
                unsigned sp = (unsigned)(grp == 0 ? p0 : grp == 1 ? p1 : grp == 2 ? p2 : p3);
                unsigned sn = (unsigned)(grp == 0 ? m0 : grp == 1 ? m1 : grp == 2 ? m2 : m3);
                if (e + grp < pde[n]) {        // exec-masked: no dummy txns
                    sp = sp < (unsigned)N ? sp : 0u;
                    uint2 pv = *((const uint2*)(src + ((size_t)sp << 6)) + q);
                    ps[n][0] += bf16lo(pv.x); ps[n][1] += bf16hi(pv.x);
                    ps[n][2] += bf16lo(pv.y); ps[n][3] += bf16hi(pv.y);
                }
                if (e + grp < nde[n]) {
                    sn = sn < (unsigned)N ? sn : 0u;
                    uint2 nv = *((const uint2*)(src + ((size_t)sn << 6)) + q);
                    ns[n][0] += bf16lo(nv.x); ns[n][1] += bf16hi(nv.x);
                    ns[n][2] += bf16lo(nv.y); ns[n][3] += bf16hi(nv.y);
                }
            }
        }
        #pragma unroll
        for (int n = 0; n < 4; ++n) {
            #pragma unroll
            for (int r = 0; r < 4; ++r) {
                ps[n][r] += __shfl_xor(ps[n][r], 16);
                ps[n][r] += __shfl_xor(ps[n][r], 32);
                ns[n][r] += __shfl_xor(ns[n][r], 16);
                ns[n][r] += __shfl_xor(ns[n][r], 32);
            }
            int i = i0 + n;
            if (i < N) {
                float invp = 1.f / fmaxf((float)pd[n], 1.f);
                float invn = 1.f / fmaxf((float)nd[n], 1.f);
                uint2* arow = (uint2*)(agg + ((size_t)i << 7));
                if (grp == 0) {
                    uint2 ow;
                    ow.x = pack2(ps[n][0] * invp, ps[n][1] * invp);
                    ow.y = pack2(ps[n][2] * invp, ps[n][3] * invp);
                    arow[q] = ow;
                } else if (grp == 1) {
                    uint2 ow;
                    ow.x = pack2(ns[n][0] * invn, ns[n][1] * invn);
                    ow.y = pack2(ns[n][2] * invn, ns[n][3] * invn);
                    arow[16 + q] = ow;
                }
            }
        }
    }
}

// ---------------------------------------------------------------------------
// GEMM1 (MFMA): z1b = tanh([ap,x]@Wp1 | [an,x]@Wn1), bf16 in / bf16 out.
// ---------------------------------------------------------------------------
__global__ __launch_bounds__(256, 3) void pg_gemm1(
    const __hip_bfloat16* __restrict__ xb, const __hip_bfloat16* __restrict__ agg,
    const float* __restrict__ Wp, const float* __restrict__ bp,
    const float* __restrict__ Wn, const float* __restrict__ bn,
    __hip_bfloat16* __restrict__ z1b, int N, int nwv)
{
    int tid = threadIdx.x;
    int w = tid >> 6, lane = tid & 63;
    int q = lane >> 4, c = lane & 15;

    bf16x8 B[2][4][2];
    #pragma unroll
    for (int kt = 0; kt < 4; ++kt)
        #pragma unroll
        for (int ct = 0; ct < 2; ++ct) {
            B[0][kt][ct] = wfrag(Wp, 32, kt, ct, q, c);
            B[1][kt][ct] = wfrag(Wn, 32, kt, ct, q, c);
        }
    float bias[2][2];
    #pragma unroll
    for (int ct = 0; ct < 2; ++ct) {
        bias[0][ct] = bp[ct * 16 + c];
        bias[1][ct] = bn[ct * 16 + c];
    }

    int ntiles = (N + 15) >> 4;
    #pragma unroll 1
    for (int t = blockIdx.x * 4 + w; t < ntiles; t += nwv) {
        int i = min(t * 16 + c, N - 1);
        const __hip_bfloat16* arow = agg + ((size_t)i << 7);
        const __hip_bfloat16* xrow = xb + ((size_t)i << 6);
        bf16x8 aA0 = afrag_bf16(arow, 0, q);
        bf16x8 aA1 = afrag_bf16(arow, 32, q);
        bf16x8 aA2 = afrag_bf16(arow, 64, q);
        bf16x8 aA3 = afrag_bf16(arow, 96, q);
        bf16x8 aX0 = afrag_bf16(xrow, 0, q);
        bf16x8 aX1 = afrag_bf16(xrow, 32, q);
        f32x4 acc[2][2];
        #pragma unroll
        for (int ct = 0; ct < 2; ++ct) {
            f32x4 a = {0.f, 0.f, 0.f, 0.f};
            a = MFMA(aA0, B[0][0][ct], a);
            a = MFMA(aA1, B[0][1][ct], a);
            a = MFMA(aX0, B[0][2][ct], a);
            a = MFMA(aX1, B[0][3][ct], a);
            acc[0][ct] = a;
            f32x4 b = {0.f, 0.f, 0.f, 0.f};
            b = MFMA(aA2, B[1][0][ct], b);
            b = MFMA(aA3, B[1][1][ct], b);
            b = MFMA(aX0, B[1][2][ct], b);
            b = MFMA(aX1, B[1][3][ct], b);
            acc[1][ct] = b;
        }
        #pragma unroll
        for (int h = 0; h < 2; ++h)
            #pragma unroll
            for (int ct = 0; ct < 2; ++ct)
                #pragma unroll
                for (int r = 0; r < 4; ++r) {
                    int row = t * 16 + q * 4 + r;
                    if (row < N)
                        z1b[(size_t)row * 64 + h * 32 + ct * 16 + c] =
                            __float2bfloat16(tanhf(acc[h][ct][r] + bias[h][ct]));
                }
    }
}

// ---------------------------------------------------------------------------
// GEMM2 (MFMA): z2 = tanh([agg-windows, z1]@Wp2 | ...@Wn2).
// z2b written bf16 into agg region cols 0..63 (stride 128) -> row-local, safe.
// ---------------------------------------------------------------------------
__global__ __launch_bounds__(256, 3) void pg_gemm2(
    const __hip_bfloat16* __restrict__ z1b, __hip_bfloat16* agg,
    const float* __restrict__ Wp2, const float* __restrict__ bp2,
    const float* __restrict__ Wn2, const float* __restrict__ bn2,
    int N, int nwv)
{
    int tid = threadIdx.x;
    int w = tid >> 6, lane = tid & 63;
    int q = lane >> 4, c = lane & 15;

    bf16x8 B[2][3][2];
    #pragma unroll
    for (int kt = 0; kt < 3; ++kt)
        #pragma unroll
        for (int ct = 0; ct < 2; ++ct) {
            B[0][kt][ct] = wfrag(Wp2, 32, kt, ct, q, c);
            B[1][kt][ct] = wfrag(Wn2, 32, kt, ct, q, c);
        }
    float bias[2][2];
    #pragma unroll
    for (int ct = 0; ct < 2; ++ct) {
        bias[0][ct] = bp2[ct * 16 + c];
        bias[1][ct] = bn2[ct * 16 + c];
    }

    int ntiles = (N + 15) >> 4;
    #pragma unroll 1
    for (int t = blockIdx.x * 4 + w; t < ntiles; t += nwv) {
        int i = min(t * 16 + c, N - 1);
        const __hip_bfloat16* arow = agg + ((size_t)i << 7);
        const __hip_bfloat16* zrow = z1b + ((size_t)i << 6);
        bf16x8 ap0 = afrag_bf16(arow, 0, q);
        bf16x8 ap1 = afrag_bf16(arow, 96, q);
        bf16x8 an0 = afrag_bf16(arow, 32, q);
        bf16x8 an1 = afrag_bf16(arow, 64, q);
        bf16x8 az0 = afrag_bf16(zrow, 0, q);
        bf16x8 az1 = afrag_bf16(zrow, 32, q);
        f32x4 acc[2][2];
        #pragma unroll
        for (int ct = 0; ct < 2; ++ct) {
            f32x4 a = {0.f, 0.f, 0.f, 0.f};
            a = MFMA(ap0, B[0][0][ct], a);
            a = MFMA(ap1, B[0][1][ct], a);
            a = MFMA(az0, B[0][2][ct], a);
            acc[0][ct] = a;
            f32x4 b = {0.f, 0.f, 0.f, 0.f};
            b = MFMA(an0, B[1][0][ct], b);
            b = MFMA(an1, B[1][1][ct], b);
            b = MFMA(az1, B[1][2][ct], b);
            acc[1][ct] = b;
        }
        #pragma unroll
        for (int h = 0; h < 2; ++h)
            #pragma unroll
            for (int ct = 0; ct < 2; ++ct)
                #pragma unroll
                for (int r = 0; r < 4; ++r) {
                    int row = t * 16 + q * 4 + r;
                    if (row < N)
                        agg[(size_t)row * 128 + h * 32 + ct * 16 + c] =
                            __float2bfloat16(tanhf(acc[h][ct][r] + bias[h][ct]));
                }
    }
}

// ---------------------------------------------------------------------------
// MLP head (MFMA chain): z = tanh(z2@Ww+bw) -> out; BN/ReLU x2; dot Wm3 ->
// sigmoid prob. z2b read bf16 (stride 128). LDS transpose between stages.
// ---------------------------------------------------------------------------
__global__ __launch_bounds__(256, 2) void pg_mlp(
    float* out, const __hip_bfloat16* __restrict__ z2b,
    const float* __restrict__ Ww,  const float* __restrict__ bw,
    const float* __restrict__ Wm1, const float* __restrict__ bm1,
    const float* __restrict__ g1,  const float* __restrict__ be1,
    const float* __restrict__ rm1, const float* __restrict__ rv1,
    const float* __restrict__ Wm2, const float* __restrict__ bm2,
    const float* __restrict__ g2,  const float* __restrict__ be2,
    const float* __restrict__ rm2, const float* __restrict__ rv2,
    const float* __restrict__ Wm3, const float* __restrict__ bm3,
    int N, int nwv)
{
    __shared__ float xpos[4][16][68];
    int tid = threadIdx.x;
    int w = tid >> 6, lane = tid & 63;
    int q = lane >> 4, c = lane & 15;
    float (*lx)[68] = xpos[w];

    bf16x8 Bw[2][4], B1[2][4], B2[2][4];
    #pragma unroll
    for (int kt = 0; kt < 2; ++kt)
        #pragma unroll
        for (int ct = 0; ct < 4; ++ct) {
            Bw[kt][ct] = wfrag(Ww,  64, kt, ct, q, c);
            B1[kt][ct] = wfrag(Wm1, 64, kt, ct, q, c);
            B2[kt][ct] = wfrag(Wm2, 64, kt, ct, q, c);
        }
    float bwv[4], s1[4], o1[4], s2[4], o2[4], w3[4];
    #pragma unroll
    for (int ct = 0; ct < 4; ++ct) {
        int cc = ct * 16 + c;
        bwv[ct] = bw[cc];
        float a = g1[cc] * rsqrtf(rv1[cc] + 1e-5f);
        s1[ct] = a; o1[ct] = (bm1[cc] - rm1[cc]) * a + be1[cc];
        float b = g2[cc] * rsqrtf(rv2[cc] + 1e-5f);
        s2[ct] = b; o2[ct] = (bm2[cc] - rm2[cc]) * b + be2[cc];
        w3[ct] = Wm3[cc];
    }
    float b3 = bm3[0];

    int ntiles = (N + 15) >> 4;
    #pragma unroll 1
    for (int t = blockIdx.x * 4 + w; t < ntiles; t += nwv) {
        int i = min(t * 16 + c, N - 1);
        const __hip_bfloat16* zrow = z2b + ((size_t)i << 7);
        bf16x8 a0 = afrag_bf16(zrow, 0, q);
        bf16x8 a1 = afrag_bf16(zrow, 32, q);
        f32x4 acc[4];

        // ---- Ww -> tanh -> final z (global + LDS) ----
        #pragma unroll
        for (int ct = 0; ct < 4; ++ct) {
            f32x4 a = {0.f, 0.f, 0.f, 0.f};
            a = MFMA(a0, Bw[0][ct], a);
            a = MFMA(a1, Bw[1][ct], a);
            acc[ct] = a;
        }
        #pragma unroll
        for (int ct = 0; ct < 4; ++ct)
            #pragma unroll
            for (int r = 0; r < 4; ++r) {
                int row = t * 16 + q * 4 + r;
                float v = tanhf(acc[ct][r] + bwv[ct]);
                if (row < N) out[(size_t)row * 64 + ct * 16 + c] = v;
                lx[q * 4 + r][ct * 16 + c] = v;
            }
        {
            const float* pr = &lx[c][0];
            float tb[8];
            *(float4*)tb       = *(const float4*)(pr + q * 8);
            *(float4*)(tb + 4) = *(const float4*)(pr + q * 8 + 4);
            a0 = packbf8(tb);
            *(float4*)tb       = *(const float4*)(pr + 32 + q * 8);
            *(float4*)(tb + 4) = *(const float4*)(pr + 32 + q * 8 + 4);
            a1 = packbf8(tb);
        }

        // ---- Wm1 -> BN -> ReLU ----
        #pragma unroll
        for (int ct = 0; ct < 4; ++ct) {
            f32x4 a = {0.f, 0.f, 0.f, 0.f};
            a = MFMA(a0, B1[0][ct], a);
            a = MFMA(a1, B1[1][ct], a);
            acc[ct] = a;
        }
        #pragma unroll
        for (int ct = 0; ct < 4; ++ct)
            #pragma unroll
            for (int r = 0; r < 4; ++r)
                lx[q * 4 + r][ct * 16 + c] = fmaxf(acc[ct][r] * s1[ct] + o1[ct], 0.f);
        {
            const float* pr = &lx[c][0];
            float tb[8];
            *(float4*)tb       = *(const float4*)(pr + q * 8);
            *(float4*)(tb + 4) = *(const float4*)(pr + q * 8 + 4);
            a0 = packbf8(tb);
            *(float4*)tb       = *(const float4*)(pr + 32 + q * 8);
            *(float4*)(tb + 4) = *(const float4*)(pr + 32 + q * 8 + 4);
            a1 = packbf8(tb);
        }

        // ---- Wm2 -> BN -> ReLU -> dot Wm3 -> sigmoid ----
        #pragma unroll
        for (int ct = 0; ct < 4; ++ct) {
            f32x4 a = {0.f, 0.f, 0.f, 0.f};
            a = MFMA(a0, B2[0][ct], a);
            a = MFMA(a1, B2[1][ct], a);
            acc[ct] = a;
        }
        float tr[4];
        #pragma unroll
        for (int r = 0; r < 4; ++r) {
            float hs = 0.f;
            #pragma unroll
            for (int ct = 0; ct < 4; ++ct) {
                float h2 = fmaxf(acc[ct][r] * s2[ct] + o2[ct], 0.f);
                hs = fmaf(h2, w3[ct], hs);
            }
            tr[r] = hs;
        }
        #pragma unroll
        for (int m = 1; m < 16; m <<= 1)
            #pragma unroll
            for (int r = 0; r < 4; ++r) tr[r] += __shfl_xor(tr[r], m, 16);
        if (c == 0) {
            #pragma unroll
            for (int r = 0; r < 4; ++r) {
                int row = t * 16 + q * 4 + r;
                if (row < N)
                    out[(size_t)N * 64 + row] = 1.f / (1.f + expf(-(tr[r] + b3)));
            }
        }
    }
}

extern "C" void kernel_launch(void* const* d_in, const int* in_sizes, int n_in,
                              void* d_out, int out_size, void* d_ws, size_t ws_size,
                              hipStream_t stream) {
    const float* x   = (const float*)d_in[0];
    const int*   ei  = (const int*)  d_in[1];
    const float* Wp1 = (const float*)d_in[2];
    const float* bp1 = (const float*)d_in[3];
    const float* Wn1 = (const float*)d_in[4];
    const float* bn1 = (const float*)d_in[5];
    const float* Wp2 = (const float*)d_in[6];
    const float* bp2 = (const float*)d_in[7];
    const float* Wn2 = (const float*)d_in[8];
    const float* bn2 = (const float*)d_in[9];
    const float* Ww  = (const float*)d_in[10];
    const float* bw  = (const float*)d_in[11];
    const float* Wm1 = (const float*)d_in[12];
    const float* bm1 = (const float*)d_in[13];
    const float* g1  = (const float*)d_in[14];
    const float* be1 = (const float*)d_in[15];
    const float* rm1 = (const float*)d_in[16];
    const float* rv1 = (const float*)d_in[17];
    const float* Wm2 = (const float*)d_in[18];
    const float* bm2 = (const float*)d_in[19];
    const float* g2  = (const float*)d_in[20];
    const float* be2 = (const float*)d_in[21];
    const float* rm2 = (const float*)d_in[22];
    const float* rv2 = (const float*)d_in[23];
    const float* Wm3 = (const float*)d_in[24];
    const float* bm3 = (const float*)d_in[25];
    float* out = (float*)d_out;

    int N = in_sizes[0] / 64;
    int E = in_sizes[1] / 3;

    // ws layout (51.2 MB for N=100K): prec | nrec | agg(bf16 N x 128, also z2b)
    int* prec = (int*)d_ws;
    int* nrec = prec + (size_t)N * RSTRIDE;
    __hip_bfloat16* agg = (__hip_bfloat16*)(nrec + (size_t)N * RSTRIDE);

    // d_out z region staging: z1b = first half, xb = second half (dead by mlp).
    __hip_bfloat16* z1b = (__hip_bfloat16*)out;                              // N x 64
    __hip_bfloat16* xb  = (__hip_bfloat16*)((char*)d_out + (size_t)N * 128); // N x 64

    // Zero the record region (counters live at rec[0] of each 128B row).
    hipMemsetAsync(d_ws, 0, 2 * (size_t)N * RSTRIDE * sizeof(int), stream);

    int buildBlocks = (E + 1023) / 1024;
    int castBlocks  = (N * 64 / 4 + 255) / 256;
    pg_build_cast<<<buildBlocks + castBlocks, 256, 0, stream>>>(
        ei, prec, nrec, E, buildBlocks, x, xb, N * 64);

    // Tail-free gather grid: exactly machine-filling at 6 blocks/CU.
    const int gatherBlocks = 1536;
    const int gb = 512, nwv = gb * 4;
    pg_gather<<<gatherBlocks, 256, 0, stream>>>(xb, prec, nrec, agg, N);
    pg_gemm1<<<gb, 256, 0, stream>>>(xb, agg, Wp1, bp1, Wn1, bn1, z1b, N, nwv);
    pg_gather<<<gatherBlocks, 256, 0, stream>>>(z1b, prec, nrec, agg, N);
    pg_gemm2<<<gb, 256, 0, stream>>>(z1b, agg, Wp2, bp2, Wn2, bn2, N, nwv);
    pg_mlp<<<gb, 256, 0, stream>>>(out, agg, Ww, bw,
                                   Wm1, bm1, g1, be1, rm1, rv1,
                                   Wm2, bm2, g2, be2, rm2, rv2,
                                   Wm3, bm3, N, nwv);
}

// Round 14
// 231.863 us; speedup vs baseline: 1.1542x; 1.0069x over previous
//
#include <hip/hip_runtime.h>
#include <hip/hip_bf16.h>

// Adjacency record: 32 ints, line-aligned. rec[0]=count, rec[1+slot]=src.
// Effective capacity 31 slots (Poisson λ≈6.25 -> overflow P ~ 1e-14).
#define RSTRIDE 32
#define RCAP    31

typedef __attribute__((ext_vector_type(8))) short bf16x8;
typedef __attribute__((ext_vector_type(4))) float f32x4;

#define MFMA(a, b, c) __builtin_amdgcn_mfma_f32_16x16x32_bf16(a, b, c, 0, 0, 0)

__device__ __forceinline__ unsigned short bf16rn(float f) {
    unsigned u = __builtin_bit_cast(unsigned, f);
    u += 0x7fffu + ((u >> 16) & 1u);
    return (unsigned short)(u >> 16);
}
__device__ __forceinline__ float bf16lo(unsigned u) {
    return __builtin_bit_cast(float, u << 16);
}
__device__ __forceinline__ float bf16hi(unsigned u) {
    return __builtin_bit_cast(float, u & 0xffff0000u);
}
__device__ __forceinline__ unsigned pack2(float a, float b) {
    return (unsigned)bf16rn(a) | ((unsigned)bf16rn(b) << 16);
}
__device__ __forceinline__ bf16x8 packbf8(const float* p) {
    bf16x8 r;
    #pragma unroll
    for (int j = 0; j < 8; ++j) r[j] = (short)bf16rn(p[j]);
    return r;
}

// B-frag from row-major f32 W[K][NN]: elem j = W[kt*32 + q*8 + j][ct*16 + c]
__device__ __forceinline__ bf16x8 wfrag(const float* __restrict__ W, int NN,
                                        int kt, int ct, int q, int c) {
    const float* base = W + (kt * 32 + q * 8) * NN + ct * 16 + c;
    float t[8];
    #pragma unroll
    for (int j = 0; j < 8; ++j) t[j] = base[j * NN];
    return packbf8(t);
}

// A-frag: row-major bf16 source, contiguous 32-col window starting at cw
__device__ __forceinline__ bf16x8 afrag_bf16(const __hip_bfloat16* row, int cw, int q) {
    return *(const bf16x8*)((const short*)row + cw + q * 8);
}

// ---------------------------------------------------------------------------
// Zero only the counter word of each record (slots are count-guarded).
// ---------------------------------------------------------------------------
__global__ __launch_bounds__(256) void pg_zero_cnt(
    int* __restrict__ prec, int* __restrict__ nrec, int N)
{
    int i = blockIdx.x * 256 + threadIdx.x;
    if (i < N) {
        prec[(size_t)i * RSTRIDE] = 0;
        nrec[(size_t)i * RSTRIDE] = 0;
    }
}

// ---------------------------------------------------------------------------
// Fused: adjacency build (4 edges/thread, counter+slots co-located in one
// line-aligned record -> ~1 line-touch per edge) + x->bf16 cast.
// ---------------------------------------------------------------------------
__global__ __launch_bounds__(256) void pg_build_cast(
    const int* __restrict__ ei,
    int* __restrict__ prec, int* __restrict__ nrec, int E, int buildBlocks,
    const float* __restrict__ x, __hip_bfloat16* __restrict__ xb, int nx)
{
    int b = blockIdx.x;
    if (b >= buildBlocks) {
        int i = ((b - buildBlocks) * 256 + threadIdx.x) * 4;
        if (i < nx) {
            float4 v = *(const float4*)(x + i);
            ushort4 o;
            o.x = bf16rn(v.x); o.y = bf16rn(v.y);
            o.z = bf16rn(v.z); o.w = bf16rn(v.w);
            *(ushort4*)((unsigned short*)xb + i) = o;
        }
        return;
    }
    int e0 = (b * 256 + threadIdx.x) * 4;
    int s[4], d[4], sg[4];
    bool ok[4];
    #pragma unroll
    for (int k = 0; k < 4; ++k) {
        int e = e0 + k;
        ok[k] = (e < E);
        int ee = ok[k] ? e : 0;
        s[k]  = ei[3 * ee + 0];
        d[k]  = ei[3 * ee + 1];
        sg[k] = ei[3 * ee + 2];
    }
    int* rec[4];
    int slot[4];
    #pragma unroll
    for (int k = 0; k < 4; ++k) {
        rec[k]  = ((sg[k] > 0) ? prec : nrec) + (size_t)d[k] * RSTRIDE;
        slot[k] = ok[k] ? atomicAdd(rec[k], 1) : RCAP;
    }
    #pragma unroll
    for (int k = 0; k < 4; ++k)
        if (slot[k] < RCAP) rec[k][1 + slot[k]] = s[k];
}

// ---------------------------------------------------------------------------
// Gather: per node, pos/neg mean of bf16 src rows -> packed bf16 agg row
//   agg[i] = [ pmean(64) | nmean(64) ]
// Tail-free wave grid-stride over 4-node groups; 4 slots per VMEM instr
// (grp=lane>>4, dwordx2 each), EXEC-MASKED (no dummy transactions).
// ---------------------------------------------------------------------------
__global__ __launch_bounds__(256, 6) void pg_gather(
    const __hip_bfloat16* __restrict__ src,
    const int* __restrict__ prec, const int* __restrict__ nrec,
    __hip_bfloat16* __restrict__ agg, int N)
{
    int tid = threadIdx.x;
    int w = tid >> 6, lane = tid & 63;
    int grp = lane >> 4;      // slot offset within the 4-slot batch
    int q   = lane & 15;      // col-quad: cols 4q..4q+3

    int gwave  = blockIdx.x * 4 + w;
    int nwaves = gridDim.x * 4;
    int ngroups = (N + 3) >> 2;

    #pragma unroll 1
    for (int g = gwave; g < ngroups; g += nwaves) {
        int i0 = g * 4;
        int pd[4], nd[4], pde[4], nde[4], pl[4], nl[4];
        #pragma unroll
        for (int n = 0; n < 4; ++n) {
            int i = min(i0 + n, N - 1);
            const int* pr = prec + (size_t)i * RSTRIDE;
            const int* nr = nrec + (size_t)i * RSTRIDE;
            pd[n] = __builtin_amdgcn_readfirstlane(pr[0]);
            nd[n] = __builtin_amdgcn_readfirstlane(nr[0]);
            pde[n] = min(pd[n], RCAP);
            nde[n] = min(nd[n], RCAP);
            pl[n] = pr[1 + (lane & 31)];   // lane 31 probes next record; never selected
            nl[n] = nr[1 + (lane & 31)];
        }
        int maxd = 0;
        #pragma unroll
        for (int n = 0; n < 4; ++n) maxd = max(maxd, max(pde[n], nde[n]));

        float ps[4][4], ns[4][4];
        #pragma unroll
        for (int n = 0; n < 4; ++n)
            #pragma unroll
            for (int r = 0; r < 4; ++r) { ps[n][r] = 0.f; ns[n][r] = 0.f; }

        #pragma unroll 1
        for (int e = 0; e < maxd; e += 4) {
            #pragma unroll
            for (int n = 0; n < 4; ++n) {
                int p0 = __builtin_amdgcn_readlane(pl[n], (e + 0) < pde[n] ? e + 0 : 0);
                int p1 = __builtin_amdgcn_readlane(pl[n], (e + 1) < pde[n] ? e + 1 : 0);
                int p2 = __builtin_amdgcn_readlane(pl[n], (e + 2) < pde[n] ? e + 2 : 0);
                int p3 = __builtin_amdgcn_readlane(pl[n], (e + 3) < pde[n] ? e + 3 : 0);
                int m0 = __builtin_amdgcn_readlane(nl[n], (e + 0) < nde[n] ? e + 0 : 0);
                int m1 = __builtin_amdgcn_readlane(nl[n], (e + 1) < nde[n] ? e + 1 : 0);
                int m2 = __builtin_amdgcn_readlane(nl[n], (e + 2) < nde[n] ? e + 2 : 0);
                int m3 = __builtin_amdgcn_readlane(nl[n], (e + 3) < nde[n] ? e + 3 : 0);
                unsigned sp = (unsigned)(grp == 0 ? p0 : grp == 1 ? p1 : grp == 2 ? p2 : p3);
                unsigned sn = (unsigned)(grp == 0 ? m0 : grp == 1 ? m1 : grp == 2 ? m2 : m3);
                if (e + grp < pde[n]) {        // exec-masked: no dummy txns
                    sp = sp < (unsigned)N ? sp : 0u;
                    uint2 pv = *((const uint2*)(src + ((size_t)sp << 6)) + q);
                    ps[n][0] += bf16lo(pv.x); ps[n][1] += bf16hi(pv.x);
                    ps[n][2] += bf16lo(pv.y); ps[n][3] += bf16hi(pv.y);
                }
                if (e + grp < nde[n]) {
                    sn = sn < (unsigned)N ? sn : 0u;
                    uint2 nv = *((const uint2*)(src + ((size_t)sn << 6)) + q);
                    ns[n][0] += bf16lo(nv.x); ns[n][1] += bf16hi(nv.x);
                    ns[n][2] += bf16lo(nv.y); ns[n][3] += bf16hi(nv.y);
                }
            }
        }
        #pragma unroll
        for (int n = 0; n < 4; ++n) {
            #pragma unroll
            for (int r = 0; r < 4; ++r) {
                ps[n][r] += __shfl_xor(ps[n][r], 16);
                ps[n][r] += __shfl_xor(ps[n][r], 32);
                ns[n][r] += __shfl_xor(ns[n][r], 16);
                ns[n][r] += __shfl_xor(ns[n][r], 32);
            }
            int i = i0 + n;
            if (i < N) {
                float invp = 1.f / fmaxf((float)pd[n], 1.f);
                float invn = 1.f / fmaxf((float)nd[n], 1.f);
                uint2* arow = (uint2*)(agg + ((size_t)i << 7));
                if (grp == 0) {
                    uint2 ow;
                    ow.x = pack2(ps[n][0] * invp, ps[n][1] * invp);
                    ow.y = pack2(ps[n][2] * invp, ps[n][3] * invp);
                    arow[q] = ow;
                } else if (grp == 1) {
                    uint2 ow;
                    ow.x = pack2(ns[n][0] * invn, ns[n][1] * invn);
                    ow.y = pack2(ns[n][2] * invn, ns[n][3] * invn);
                    arow[16 + q] = ow;
                }
            }
        }
    }
}

// ---------------------------------------------------------------------------
// GEMM1 (MFMA): z1b = tanh([ap,x]@Wp1 | [an,x]@Wn1), bf16 in / bf16 out.
// ---------------------------------------------------------------------------
__global__ __launch_bounds__(256, 3) void pg_gemm1(
    const __hip_bfloat16* __restrict__ xb, const __hip_bfloat16* __restrict__ agg,
    const float* __restrict__ Wp, const float* __restrict__ bp,
    const float* __restrict__ Wn, const float* __restrict__ bn,
    __hip_bfloat16* __restrict__ z1b, int N, int nwv)
{
    int tid = threadIdx.x;
    int w = tid >> 6, lane = tid & 63;
    int q = lane >> 4, c = lane & 15;

    bf16x8 B[2][4][2];
    #pragma unroll
    for (int kt = 0; kt < 4; ++kt)
        #pragma unroll
        for (int ct = 0; ct < 2; ++ct) {
            B[0][kt][ct] = wfrag(Wp, 32, kt, ct, q, c);
            B[1][kt][ct] = wfrag(Wn, 32, kt, ct, q, c);
        }
    float bias[2][2];
    #pragma unroll
    for (int ct = 0; ct < 2; ++ct) {
        bias[0][ct] = bp[ct * 16 + c];
        bias[1][ct] = bn[ct * 16 + c];
    }

    int ntiles = (N + 15) >> 4;
    #pragma unroll 1
    for (int t = blockIdx.x * 4 + w; t < ntiles; t += nwv) {
        int i = min(t * 16 + c, N - 1);
        const __hip_bfloat16* arow = agg + ((size_t)i << 7);
        const __hip_bfloat16* xrow = xb + ((size_t)i << 6);
        bf16x8 aA0 = afrag_bf16(arow, 0, q);
        bf16x8 aA1 = afrag_bf16(arow, 32, q);
        bf16x8 aA2 = afrag_bf16(arow, 64, q);
        bf16x8 aA3 = afrag_bf16(arow, 96, q);
        bf16x8 aX0 = afrag_bf16(xrow, 0, q);
        bf16x8 aX1 = afrag_bf16(xrow, 32, q);
        f32x4 acc[2][2];
        #pragma unroll
        for (int ct = 0; ct < 2; ++ct) {
            f32x4 a = {0.f, 0.f, 0.f, 0.f};
            a = MFMA(aA0, B[0][0][ct], a);
            a = MFMA(aA1, B[0][1][ct], a);
            a = MFMA(aX0, B[0][2][ct], a);
            a = MFMA(aX1, B[0][3][ct], a);
            acc[0][ct] = a;
            f32x4 b = {0.f, 0.f, 0.f, 0.f};
            b = MFMA(aA2, B[1][0][ct], b);
            b = MFMA(aA3, B[1][1][ct], b);
            b = MFMA(aX0, B[1][2][ct], b);
            b = MFMA(aX1, B[1][3][ct], b);
            acc[1][ct] = b;
        }
        #pragma unroll
        for (int h = 0; h < 2; ++h)
            #pragma unroll
            for (int ct = 0; ct < 2; ++ct)
                #pragma unroll
                for (int r = 0; r < 4; ++r) {
                    int row = t * 16 + q * 4 + r;
                    if (row < N)
                        z1b[(size_t)row * 64 + h * 32 + ct * 16 + c] =
                            __float2bfloat16(tanhf(acc[h][ct][r] + bias[h][ct]));
                }
    }
}

// ---------------------------------------------------------------------------
// GEMM2 (MFMA): z2 = tanh([agg-windows, z1]@Wp2 | ...@Wn2).
// z2b written bf16 into agg region cols 0..63 (stride 128) -> row-local, safe.
// ---------------------------------------------------------------------------
__global__ __launch_bounds__(256, 3) void pg_gemm2(
    const __hip_bfloat16* __restrict__ z1b, __hip_bfloat16* agg,
    const float* __restrict__ Wp2, const float* __restrict__ bp2,
    const float* __restrict__ Wn2, const float* __restrict__ bn2,
    int N, int nwv)
{
    int tid = threadIdx.x;
    int w = tid >> 6, lane = tid & 63;
    int q = lane >> 4, c = lane & 15;

    bf16x8 B[2][3][2];
    #pragma unroll
    for (int kt = 0; kt < 3; ++kt)
        #pragma unroll
        for (int ct = 0; ct < 2; ++ct) {
            B[0][kt][ct] = wfrag(Wp2, 32, kt, ct, q, c);
            B[1][kt][ct] = wfrag(Wn2, 32, kt, ct, q, c);
        }
    float bias[2][2];
    #pragma unroll
    for (int ct = 0; ct < 2; ++ct) {
        bias[0][ct] = bp2[ct * 16 + c];
        bias[1][ct] = bn2[ct * 16 + c];
    }

    int ntiles = (N + 15) >> 4;
    #pragma unroll 1
    for (int t = blockIdx.x * 4 + w; t < ntiles; t += nwv) {
        int i = min(t * 16 + c, N - 1);
        const __hip_bfloat16* arow = agg + ((size_t)i << 7);
        const __hip_bfloat16* zrow = z1b + ((size_t)i << 6);
        bf16x8 ap0 = afrag_bf16(arow, 0, q);
        bf16x8 ap1 = afrag_bf16(arow, 96, q);
        bf16x8 an0 = afrag_bf16(arow, 32, q);
        bf16x8 an1 = afrag_bf16(arow, 64, q);
        bf16x8 az0 = afrag_bf16(zrow, 0, q);
        bf16x8 az1 = afrag_bf16(zrow, 32, q);
        f32x4 acc[2][2];
        #pragma unroll
        for (int ct = 0; ct < 2; ++ct) {
            f32x4 a = {0.f, 0.f, 0.f, 0.f};
            a = MFMA(ap0, B[0][0][ct], a);
            a = MFMA(ap1, B[0][1][ct], a);
            a = MFMA(az0, B[0][2][ct], a);
            acc[0][ct] = a;
            f32x4 b = {0.f, 0.f, 0.f, 0.f};
            b = MFMA(an0, B[1][0][ct], b);
            b = MFMA(an1, B[1][1][ct], b);
            b = MFMA(az1, B[1][2][ct], b);
            acc[1][ct] = b;
        }
        #pragma unroll
        for (int h = 0; h < 2; ++h)
            #pragma unroll
            for (int ct = 0; ct < 2; ++ct)
                #pragma unroll
                for (int r = 0; r < 4; ++r) {
                    int row = t * 16 + q * 4 + r;
                    if (row < N)
                        agg[(size_t)row * 128 + h * 32 + ct * 16 + c] =
                            __float2bfloat16(tanhf(acc[h][ct][r] + bias[h][ct]));
                }
    }
}

// ---------------------------------------------------------------------------
// MLP head (MFMA chain): z = tanh(z2@Ww+bw) -> out; BN/ReLU x2; dot Wm3 ->
// sigmoid prob. z2b read bf16 (stride 128). LDS transpose between stages.
// ---------------------------------------------------------------------------
__global__ __launch_bounds__(256, 2) void pg_mlp(
    float* out, const __hip_bfloat16* __restrict__ z2b,
    const float* __restrict__ Ww,  const float* __restrict__ bw,
    const float* __restrict__ Wm1, const float* __restrict__ bm1,
    const float* __restrict__ g1,  const float* __restrict__ be1,
    const float* __restrict__ rm1, const float* __restrict__ rv1,
    const float* __restrict__ Wm2, const float* __restrict__ bm2,
    const float* __restrict__ g2,  const float* __restrict__ be2,
    const float* __restrict__ rm2, const float* __restrict__ rv2,
    const float* __restrict__ Wm3, const float* __restrict__ bm3,
    int N, int nwv)
{
    __shared__ float xpos[4][16][68];
    int tid = threadIdx.x;
    int w = tid >> 6, lane = tid & 63;
    int q = lane >> 4, c = lane & 15;
    float (*lx)[68] = xpos[w];

    bf16x8 Bw[2][4], B1[2][4], B2[2][4];
    #pragma unroll
    for (int kt = 0; kt < 2; ++kt)
        #pragma unroll
        for (int ct = 0; ct < 4; ++ct) {
            Bw[kt][ct] = wfrag(Ww,  64, kt, ct, q, c);
            B1[kt][ct] = wfrag(Wm1, 64, kt, ct, q, c);
            B2[kt][ct] = wfrag(Wm2, 64, kt, ct, q, c);
        }
    float bwv[4], s1[4], o1[4], s2[4], o2[4], w3[4];
    #pragma unroll
    for (int ct = 0; ct < 4; ++ct) {
        int cc = ct * 16 + c;
        bwv[ct] = bw[cc];
        float a = g1[cc] * rsqrtf(rv1[cc] + 1e-5f);
        s1[ct] = a; o1[ct] = (bm1[cc] - rm1[cc]) * a + be1[cc];
        float b = g2[cc] * rsqrtf(rv2[cc] + 1e-5f);
        s2[ct] = b; o2[ct] = (bm2[cc] - rm2[cc]) * b + be2[cc];
        w3[ct] = Wm3[cc];
    }
    float b3 = bm3[0];

    int ntiles = (N + 15) >> 4;
    #pragma unroll 1
    for (int t = blockIdx.x * 4 + w; t < ntiles; t += nwv) {
        int i = min(t * 16 + c, N - 1);
        const __hip_bfloat16* zrow = z2b + ((size_t)i << 7);
        bf16x8 a0 = afrag_bf16(zrow, 0, q);
        bf16x8 a1 = afrag_bf16(zrow, 32, q);
        f32x4 acc[4];

        // ---- Ww -> tanh -> final z (global + LDS) ----
        #pragma unroll
        for (int ct = 0; ct < 4; ++ct) {
            f32x4 a = {0.f, 0.f, 0.f, 0.f};
            a = MFMA(a0, Bw[0][ct], a);
            a = MFMA(a1, Bw[1][ct], a);
            acc[ct] = a;
        }
        #pragma unroll
        for (int ct = 0; ct < 4; ++ct)
            #pragma unroll
            for (int r = 0; r < 4; ++r) {
                int row = t * 16 + q * 4 + r;
                float v = tanhf(acc[ct][r] + bwv[ct]);
                if (row < N) out[(size_t)row * 64 + ct * 16 + c] = v;
                lx[q * 4 + r][ct * 16 + c] = v;
            }
        {
            const float* pr = &lx[c][0];
            float tb[8];
            *(float4*)tb       = *(const float4*)(pr + q * 8);
            *(float4*)(tb + 4) = *(const float4*)(pr + q * 8 + 4);
            a0 = packbf8(tb);
            *(float4*)tb       = *(const float4*)(pr + 32 + q * 8);
            *(float4*)(tb + 4) = *(const float4*)(pr + 32 + q * 8 + 4);
            a1 = packbf8(tb);
        }

        // ---- Wm1 -> BN -> ReLU ----
        #pragma unroll
        for (int ct = 0; ct < 4; ++ct) {
            f32x4 a = {0.f, 0.f, 0.f, 0.f};
            a = MFMA(a0, B1[0][ct], a);
            a = MFMA(a1, B1[1][ct], a);
            acc[ct] = a;
        }
        #pragma unroll
        for (int ct = 0; ct < 4; ++ct)
            #pragma unroll
            for (int r = 0; r < 4; ++r)
                lx[q * 4 + r][ct * 16 + c] = fmaxf(acc[ct][r] * s1[ct] + o1[ct], 0.f);
        {
            const float* pr = &lx[c][0];
            float tb[8];
            *(float4*)tb       = *(const float4*)(pr + q * 8);
            *(float4*)(tb + 4) = *(const float4*)(pr + q * 8 + 4);
            a0 = packbf8(tb);
            *(float4*)tb       = *(const float4*)(pr + 32 + q * 8);
            *(float4*)(tb + 4) = *(const float4*)(pr + 32 + q * 8 + 4);
            a1 = packbf8(tb);
        }

        // ---- Wm2 -> BN -> ReLU -> dot Wm3 -> sigmoid ----
        #pragma unroll
        for (int ct = 0; ct < 4; ++ct) {
            f32x4 a = {0.f, 0.f, 0.f, 0.f};
            a = MFMA(a0, B2[0][ct], a);
            a = MFMA(a1, B2[1][ct], a);
            acc[ct] = a;
        }
        float tr[4];
        #pragma unroll
        for (int r = 0; r < 4; ++r) {
            float hs = 0.f;
            #pragma unroll
            for (int ct = 0; ct < 4; ++ct) {
                float h2 = fmaxf(acc[ct][r] * s2[ct] + o2[ct], 0.f);
                hs = fmaf(h2, w3[ct], hs);
            }
            tr[r] = hs;
        }
        #pragma unroll
        for (int m = 1; m < 16; m <<= 1)
            #pragma unroll
            for (int r = 0; r < 4; ++r) tr[r] += __shfl_xor(tr[r], m, 16);
        if (c == 0) {
            #pragma unroll
            for (int r = 0; r < 4; ++r) {
                int row = t * 16 + q * 4 + r;
                if (row < N)
                    out[(size_t)N * 64 + row] = 1.f / (1.f + expf(-(tr[r] + b3)));
            }
        }
    }
}

extern "C" void kernel_launch(void* const* d_in, const int* in_sizes, int n_in,
                              void* d_out, int out_size, void* d_ws, size_t ws_size,
                              hipStream_t stream) {
    const float* x   = (const float*)d_in[0];
    const int*   ei  = (const int*)  d_in[1];
    const float* Wp1 = (const float*)d_in[2];
    const float* bp1 = (const float*)d_in[3];
    const float* Wn1 = (const float*)d_in[4];
    const float* bn1 = (const float*)d_in[5];
    const float* Wp2 = (const float*)d_in[6];
    const float* bp2 = (const float*)d_in[7];
    const float* Wn2 = (const float*)d_in[8];
    const float* bn2 = (const float*)d_in[9];
    const float* Ww  = (const float*)d_in[10];
    const float* bw  = (const float*)d_in[11];
    const float* Wm1 = (const float*)d_in[12];
    const float* bm1 = (const float*)d_in[13];
    const float* g1  = (const float*)d_in[14];
    const float* be1 = (const float*)d_in[15];
    const float* rm1 = (const float*)d_in[16];
    const float* rv1 = (const float*)d_in[17];
    const float* Wm2 = (const float*)d_in[18];
    const float* bm2 = (const float*)d_in[19];
    const float* g2  = (const float*)d_in[20];
    const float* be2 = (const float*)d_in[21];
    const float* rm2 = (const float*)d_in[22];
    const float* rv2 = (const float*)d_in[23];
    const float* Wm3 = (const float*)d_in[24];
    const float* bm3 = (const float*)d_in[25];
    float* out = (float*)d_out;

    int N = in_sizes[0] / 64;
    int E = in_sizes[1] / 3;

    // ws layout (51.2 MB for N=100K): prec | nrec | agg(bf16 N x 128, also z2b)
    int* prec = (int*)d_ws;
    int* nrec = prec + (size_t)N * RSTRIDE;
    __hip_bfloat16* agg = (__hip_bfloat16*)(nrec + (size_t)N * RSTRIDE);

    // d_out z region staging: z1b = first half, xb = second half (dead by mlp).
    __hip_bfloat16* z1b = (__hip_bfloat16*)out;                              // N x 64
    __hip_bfloat16* xb  = (__hip_bfloat16*)((char*)d_out + (size_t)N * 128); // N x 64

    // Zero only the per-record counters (slots are count-guarded).
    pg_zero_cnt<<<(N + 255) / 256, 256, 0, stream>>>(prec, nrec, N);

    int buildBlocks = (E + 1023) / 1024;
    int castBlocks  = (N * 64 / 4 + 255) / 256;
    pg_build_cast<<<buildBlocks + castBlocks, 256, 0, stream>>>(
        ei, prec, nrec, E, buildBlocks, x, xb, N * 64);

    // Tail-free gather grid (6 blocks/CU); machine-filling gemm grid (3/CU).
    const int gatherBlocks = 1536;
    const int gemmBlocks = 768, gemmWaves = gemmBlocks * 4;
    const int mlpBlocks = 512, mlpWaves = mlpBlocks * 4;
    pg_gather<<<gatherBlocks, 256, 0, stream>>>(xb, prec, nrec, agg, N);
    pg_gemm1<<<gemmBlocks, 256, 0, stream>>>(xb, agg, Wp1, bp1, Wn1, bn1, z1b, N, gemmWaves);
    pg_gather<<<gatherBlocks, 256, 0, stream>>>(z1b, prec, nrec, agg, N);
    pg_gemm2<<<gemmBlocks, 256, 0, stream>>>(z1b, agg, Wp2, bp2, Wn2, bn2, N, gemmWaves);
    pg_mlp<<<mlpBlocks, 256, 0, stream>>>(out, agg, Ww, bw,
                                          Wm1, bm1, g1, be1, rm1, rv1,
                                          Wm2, bm2, g2, be2, rm2, rv2,
                                          Wm3, bm3, N, mlpWaves);
}